// Round 9
// baseline (6933.642 us; speedup 1.0000x reference)
//
#include <hip/hip_runtime.h>
#include <hip/hip_bf16.h>

#define SS 128
#define TT 128
#define NBLK 256
#define FSTRIDE 16   // one flag per 64B cacheline

typedef __attribute__((ext_vector_type(8))) short bf16x8;
typedef __attribute__((ext_vector_type(4))) float f32x4;
typedef unsigned short ushort_t;

__device__ __forceinline__ float sigf(float x) { return 1.f / (1.f + __expf(-x)); }

__device__ __forceinline__ ushort_t f2bf(float f) {   // RNE f32 -> bf16
  unsigned b = __builtin_bit_cast(unsigned, f);
  return (ushort_t)((b + 0x7FFFu + ((b >> 16) & 1u)) >> 16);
}
__device__ __forceinline__ float bf2f(ushort_t u) {
  return __builtin_bit_cast(float, (unsigned)u << 16);
}

// Write-through coherent bf16 store (to MALL): cross-block producers.
__device__ __forceinline__ void cstoreh(ushort_t* p, ushort_t v) {
  __hip_atomic_store(p, v, __ATOMIC_RELAXED, __HIP_MEMORY_SCOPE_AGENT);
}

// ---------------------------------------------------------------------------
// 2-hop device-wide barrier: "last-arriver broadcasts".
//   hop 1: each block's thread0 fetch_add's the generation counter; the RMW
//          return value IS the arrival detection (no master poll hop).
//   hop 2: the last arriver's 256 threads release per-block go lines
//          (1 writer + 1 reader per line, contention-free); others spin on
//          their own line. Counter is generation-indexed (no reset).
// Data ordering: __syncthreads() drains each wave's stores (compiler emits
// s_waitcnt vmcnt(0) before s_barrier); counter==256 => all data visible.
__device__ __forceinline__ void gbar(unsigned* cnt, unsigned* go, unsigned gen) {
  __syncthreads();
  __shared__ int amLast;
  int tid = threadIdx.x;
  if (tid == 0) {
    asm volatile("s_waitcnt vmcnt(0)" ::: "memory");
    unsigned r = __hip_atomic_fetch_add(&cnt[(gen - 1) * FSTRIDE], 1u,
                                        __ATOMIC_RELAXED, __HIP_MEMORY_SCOPE_AGENT);
    amLast = (r == NBLK - 1u);
  }
  __syncthreads();
  if (amLast) {
    __hip_atomic_store(&go[tid * FSTRIDE], gen, __ATOMIC_RELAXED,
                       __HIP_MEMORY_SCOPE_AGENT);
  } else if (tid == 0) {
    int guard = 0;
    while (__hip_atomic_load(&go[blockIdx.x * FSTRIDE], __ATOMIC_RELAXED,
                             __HIP_MEMORY_SCOPE_AGENT) < gen &&
           ++guard < (1 << 20))
      __builtin_amdgcn_s_sleep(1);
  }
  __syncthreads();
  asm volatile("" ::: "memory");
}

// ---------------------------------------------------------------------------
__global__ void k_embed(const float* __restrict__ emb, const int* __restrict__ toks,
                        float* __restrict__ out, int seqlen) {
  int s = blockIdx.x >> 6, b = blockIdx.x & 63;
  int tok = toks[b * seqlen + s];
  const float4* src = (const float4*)(emb + (size_t)tok * 512);
  float4* dst = (float4*)(out + (size_t)blockIdx.x * 512);
  dst[threadIdx.x] = src[threadIdx.x];
}

// ---------------------------------------------------------------------------
// fp32 GEMM (input-gate precompute + final projection).
// MODE 1: C[((m>>6)*ldc + n)*64 + (m&63)]   MODE 2: out[((m&63)*512+n)*128+(m>>6)]
template<int MODE>
__global__ __launch_bounds__(256) void k_gemm(
    const float* __restrict__ X, int ldx,
    const float* __restrict__ W, int ldw, int koff,
    const float* __restrict__ b1, const float* __restrict__ b2,
    float* __restrict__ C, int ldc, int K) {
  __shared__ float Xs[16][132];
  __shared__ float Ws[16][132];
  int m0 = blockIdx.y * 128, n0 = blockIdx.x * 128;
  int tx = threadIdx.x & 15, ty = threadIdx.x >> 4;
  float acc[8][8] = {};
  for (int k0 = 0; k0 < K; k0 += 16) {
    __syncthreads();
#pragma unroll
    for (int j = 0; j < 2; ++j) {
      int f4 = threadIdx.x + j * 256;
      int row = f4 >> 2, kc = (f4 & 3) * 4;
      float4 xv = *(const float4*)&X[(size_t)(m0 + row) * ldx + k0 + kc];
      Xs[kc + 0][row] = xv.x; Xs[kc + 1][row] = xv.y;
      Xs[kc + 2][row] = xv.z; Xs[kc + 3][row] = xv.w;
      float4 wv = *(const float4*)&W[(size_t)(n0 + row) * ldw + koff + k0 + kc];
      Ws[kc + 0][row] = wv.x; Ws[kc + 1][row] = wv.y;
      Ws[kc + 2][row] = wv.z; Ws[kc + 3][row] = wv.w;
    }
    __syncthreads();
#pragma unroll
    for (int kk = 0; kk < 16; ++kk) {
      float a[8], w[8];
      *(float4*)&a[0] = *(const float4*)&Xs[kk][ty * 8];
      *(float4*)&a[4] = *(const float4*)&Xs[kk][ty * 8 + 4];
      *(float4*)&w[0] = *(const float4*)&Ws[kk][tx * 8];
      *(float4*)&w[4] = *(const float4*)&Ws[kk][tx * 8 + 4];
#pragma unroll
      for (int i = 0; i < 8; ++i)
#pragma unroll
        for (int j = 0; j < 8; ++j)
          acc[i][j] += a[i] * w[j];
    }
  }
  float bias[8];
#pragma unroll
  for (int j = 0; j < 8; ++j) {
    int n = n0 + tx * 8 + j;
    bias[j] = (b1 ? b1[n] : 0.f) + (b2 ? b2[n] : 0.f);
  }
  for (int i = 0; i < 8; ++i) {
    int m = m0 + ty * 8 + i;
#pragma unroll
    for (int j = 0; j < 8; ++j) {
      int n = n0 + tx * 8 + j;
      float v = acc[i][j] + bias[j];
      if (MODE == 1)
        C[((size_t)(m >> 6) * ldc + n) * 64 + (m & 63)] = v;
      else
        C[((size_t)(m & 63) * 512 + n) * 128 + (m >> 6)] = v;
    }
  }
}

// ---------------------------------------------------------------------------
// MFMA fragment conventions (mfma_f32_16x16x32_bf16):
//   A: lane l holds m=l&15, k=(l>>4)*8+i ; B: lane l holds n=l&15, same k
//   D: lane l reg r holds m=(l>>4)*4+r, n=l&15
// Per block: G[16 rows][64 b] = W[16][K]*X[K][64]; wave wv owns batches
// wv*16..+15. Rows 0-3 = gates i,f,g,o of hu0; 4-7 = of hu1; 8-15 pad.
// Epilogue lanes 0-31: regs = 4 gates of one (hu,b).

// Persistent encoder layer: K=256, ring ringE[129][2][64][256] bf16.
template<int LOUT>
__global__ __launch_bounds__(256, 1) void enc_persist(
    const float* __restrict__ GT,     // [128][2048][64] input gates fp32
    const float* __restrict__ whh,    // [2][1024][256] this layer fp32
    ushort_t* __restrict__ ringE,     // [129][2][64][256] bf16
    float* __restrict__ lout,
    ushort_t* __restrict__ hFin,      // dec ring slot0 [64][1024]; 512+d*256+hu
    float* __restrict__ cFin,         // [512][64] fp32
    unsigned* cnt, unsigned* go) {
  int nb = blockIdx.x;
  int d = nb >> 7, nbL = nb & 127;
  int tid = threadIdx.x;
  int lane = tid & 63;
  int wv = __builtin_amdgcn_readfirstlane(tid >> 6);
  int l16 = lane & 15, kg = lane >> 4;
  __shared__ ushort_t wE[16 * 264];

  for (int idx = tid; idx < 16 * 256; idx += 256) {
    int m = idx >> 8, k = idx & 255;
    float v = 0.f;
    if (m < 8)
      v = whh[(size_t)d * 262144 +
              (size_t)((m & 3) * 256 + nbL + 128 * (m >> 2)) * 256 + k];
    wE[m * 264 + k] = f2bf(v);
  }
  __syncthreads();

  int b = wv * 16 + l16;
  int hu = nbL + 128 * kg;            // epilogue lanes (<32)
  float creg = 0.f;
  const ushort_t* wp = wE + l16 * 264 + kg * 8;

  for (int t = 0; t < SS; ++t) {
    int s = d ? (SS - 1 - t) : t;
    float gi[4];
    if (lane < 32) {                  // hoisted: issue during MFMA latency
#pragma unroll
      for (int r = 0; r < 4; ++r)
        gi[r] = GT[((size_t)s * 2048 + d * 1024 + r * 256 + hu) * 64 + b];
    }
    f32x4 acc = {0.f, 0.f, 0.f, 0.f};
    const ushort_t* xb = ringE + ((size_t)(t * 2 + d) * 64 + b) * 256 + kg * 8;
#pragma unroll
    for (int ks = 0; ks < 8; ++ks) {
      bf16x8 af = *(const bf16x8*)(wp + ks * 32);
      bf16x8 bf = *(const bf16x8*)(xb + ks * 32);
      acc = __builtin_amdgcn_mfma_f32_16x16x32_bf16(af, bf, acc, 0, 0, 0);
    }
    if (lane < 32) {
      float g4[4];
#pragma unroll
      for (int r = 0; r < 4; ++r) g4[r] = acc[r] + gi[r];
      float ig = sigf(g4[0]), fg = sigf(g4[1]), gg = tanhf(g4[2]), og = sigf(g4[3]);
      creg = fg * creg + ig * gg;
      float hn = og * tanhf(creg);
      cstoreh(&ringE[((size_t)((t + 1) * 2 + d) * 64 + b) * 256 + hu], f2bf(hn));
      if (LOUT == 0)
        lout[((size_t)s * 64 + b) * 512 + d * 256 + hu] = hn;
      else
        lout[(size_t)b * 65536 + (size_t)s * 512 + d * 256 + hu] = hn;
      if (t == SS - 1) {
        hFin[(size_t)b * 1024 + 512 + d * 256 + hu] = f2bf(hn);
        cFin[(d * 256 + hu) * 64 + b] = creg;
      }
    }
    if (t < SS - 1) gbar(cnt, go, (unsigned)(t + 1));
  }
}

// ---------------------------------------------------------------------------
// Persistent decoder: 128 steps x {cell0, cell1, attention, outproj}.
// bf16 rings [slot][64 b][1024 k]: r0=[feed|h0], r1=[h0|h1], r2=[ctx|h1].
__global__ __launch_bounds__(256, 1) void dec_persist(
    const float* __restrict__ GdT,    // [128][2048][64] emb gates fp32
    const float* __restrict__ w_ih0, const float* __restrict__ w_hh0,
    const float* __restrict__ w_ih1, const float* __restrict__ w_hh1,
    const float* __restrict__ b_ih1, const float* __restrict__ b_hh1,
    const float* __restrict__ attn_w,
    const float* __restrict__ enc_out,   // [64][128][512] fp32
    const int* __restrict__ src_tokens,
    const float* __restrict__ c0T, const float* __restrict__ c1T,  // [512][64]
    ushort_t* __restrict__ r0, ushort_t* __restrict__ r1,
    ushort_t* __restrict__ r2,
    float* __restrict__ houts,        // [8192][512] fp32
    unsigned* cnt, unsigned* go) {
  int nb = blockIdx.x;
  int tid = threadIdx.x;
  int lane = tid & 63;
  int wv = __builtin_amdgcn_readfirstlane(tid >> 6);
  int l16 = lane & 15, kg = lane >> 4;
  __shared__ ushort_t wAl[16 * 1032];
  __shared__ ushort_t wBl[16 * 1032];
  __shared__ ushort_t wDl[16 * 1032];
  __shared__ float h1s[512];
  __shared__ float sc[128];

  // ---- stage bf16 weights (once). Rows 0-3: gates hu=nb; 4-7: hu=nb+256.
  for (int idx = tid; idx < 16384; idx += 256) {
    int m = idx >> 10, k = idx & 1023;
    float va = 0.f, vb = 0.f, vd = 0.f;
    if (m < 8) {
      int row = (m & 3) * 512 + nb + 256 * (m >> 2);
      va = (k < 512) ? w_ih0[(size_t)row * 1024 + 512 + k]
                     : w_hh0[(size_t)row * 512 + (k - 512)];
      vb = (k < 512) ? w_ih1[(size_t)row * 512 + k]
                     : w_hh1[(size_t)row * 512 + (k - 512)];
    }
    if (m < 2) vd = attn_w[(size_t)(nb * 2 + m) * 1024 + k];
    wAl[m * 1032 + k] = f2bf(va);
    wBl[m * 1032 + k] = f2bf(vb);
    wDl[m * 1032 + k] = f2bf(vd);
  }
  __syncthreads();

  int b = wv * 16 + l16;
  int hu = nb + 256 * kg;             // epilogue lanes (<32)
  float c0r = 0.f, c1r = 0.f, bias1[4] = {0.f, 0.f, 0.f, 0.f};
  if (lane < 32) {
    c0r = c0T[hu * 64 + b];
    c1r = c1T[hu * 64 + b];
#pragma unroll
    for (int r = 0; r < 4; ++r)
      bias1[r] = b_ih1[r * 512 + hu] + b_hh1[r * 512 + hu];
  }
  const ushort_t* wpA = wAl + l16 * 1032 + kg * 8;
  const ushort_t* wpB = wBl + l16 * 1032 + kg * 8;
  const ushort_t* wpD = wDl + l16 * 1032 + kg * 8;

  for (int t = 0; t < TT; ++t) {
    unsigned gb = (unsigned)(t * 4);
    size_t sC = (size_t)t * 65536, sN = (size_t)(t + 1) * 65536;
    // ---- A: cell0 (x = [feed(t)|h0(t)] = r0 slot t) ----
    {
      float giA[4];
      if (lane < 32) {                // hoisted GdT loads
#pragma unroll
        for (int r = 0; r < 4; ++r)
          giA[r] = GdT[((size_t)t * 2048 + r * 512 + hu) * 64 + b];
      }
      f32x4 acc = {0.f, 0.f, 0.f, 0.f};
      const ushort_t* xb = r0 + sC + (size_t)b * 1024 + kg * 8;
#pragma unroll 8
      for (int ks = 0; ks < 32; ++ks) {
        bf16x8 af = *(const bf16x8*)(wpA + ks * 32);
        bf16x8 bf = *(const bf16x8*)(xb + ks * 32);
        acc = __builtin_amdgcn_mfma_f32_16x16x32_bf16(af, bf, acc, 0, 0, 0);
      }
      if (lane < 32) {
        float g4[4];
#pragma unroll
        for (int r = 0; r < 4; ++r) g4[r] = acc[r] + giA[r];
        float ig = sigf(g4[0]), fg = sigf(g4[1]), gg = tanhf(g4[2]), og = sigf(g4[3]);
        c0r = fg * c0r + ig * gg;
        float hn = og * tanhf(c0r);
        ushort_t hb = f2bf(hn);
        cstoreh(&r0[sN + (size_t)b * 1024 + 512 + hu], hb);
        cstoreh(&r1[sC + (size_t)b * 1024 + hu], hb);
      }
    }
    gbar(cnt, go, gb + 1);
    // ---- B: cell1 (x = [h0(t)|h1(t-1)] = r1 slot t) ----
    {
      f32x4 acc = {0.f, 0.f, 0.f, 0.f};
      const ushort_t* xb = r1 + sC + (size_t)b * 1024 + kg * 8;
#pragma unroll 8
      for (int ks = 0; ks < 32; ++ks) {
        bf16x8 af = *(const bf16x8*)(wpB + ks * 32);
        bf16x8 bf = *(const bf16x8*)(xb + ks * 32);
        acc = __builtin_amdgcn_mfma_f32_16x16x32_bf16(af, bf, acc, 0, 0, 0);
      }
      if (lane < 32) {
        float g4[4];
#pragma unroll
        for (int r = 0; r < 4; ++r) g4[r] = acc[r] + bias1[r];
        float ig = sigf(g4[0]), fg = sigf(g4[1]), gg = tanhf(g4[2]), og = sigf(g4[3]);
        c1r = fg * c1r + ig * gg;
        float hn = og * tanhf(c1r);
        ushort_t hb = f2bf(hn);
        cstoreh(&r1[sN + (size_t)b * 1024 + 512 + hu], hb);
        cstoreh(&r2[sC + (size_t)b * 1024 + 512 + hu], hb);
      }
    }
    gbar(cnt, go, gb + 2);
    // ---- C: attention (blocks 0..63, one per batch; fp32) ----
    if (nb < 64) {
      const ushort_t* h1b = r1 + sN + (size_t)nb * 1024 + 512;
      const float* eb = enc_out + (size_t)nb * 65536;
      for (int i = tid; i < 512; i += 256) h1s[i] = bf2f(h1b[i]);
      __syncthreads();
      {
        int s2 = tid >> 1, half = tid & 1;
        const float* er = eb + (size_t)s2 * 512 + half * 256;
        const float* hh = h1s + half * 256;
        float a = 0.f;
#pragma unroll 8
        for (int k = 0; k < 256; k += 4) {
          float4 ev = *(const float4*)&er[k];
          a += ev.x * hh[k] + ev.y * hh[k + 1] + ev.z * hh[k + 2] + ev.w * hh[k + 3];
        }
        a += __shfl_xor(a, 1);
        if (!half) sc[s2] = (src_tokens[nb * SS + s2] == 0) ? -1e30f : a;
      }
      __syncthreads();
      if (tid < 64) {
        float m = fmaxf(sc[tid], sc[tid + 64]);
        for (int off = 32; off; off >>= 1) m = fmaxf(m, __shfl_xor(m, off));
        float e0 = __expf(sc[tid] - m), e1 = __expf(sc[tid + 64] - m);
        float ssum = e0 + e1;
        for (int off = 32; off; off >>= 1) ssum += __shfl_xor(ssum, off);
        float inv = 1.f / ssum;
        sc[tid] = e0 * inv; sc[tid + 64] = e1 * inv;
      }
      __syncthreads();
      float a0 = 0.f, a1 = 0.f;
      for (int s2 = 0; s2 < 128; ++s2) {
        float p_ = sc[s2];
        const float* er = eb + (size_t)s2 * 512;
        a0 += p_ * er[tid];
        a1 += p_ * er[tid + 256];
      }
      cstoreh(&r2[sC + (size_t)nb * 1024 + tid], f2bf(a0));
      cstoreh(&r2[sC + (size_t)nb * 1024 + tid + 256], f2bf(a1));
    }
    gbar(cnt, go, gb + 3);
    // ---- D: outproj tanh([ctx|h1] @ attn_w^T) -> feed + houts ----
    {
      f32x4 acc = {0.f, 0.f, 0.f, 0.f};
      const ushort_t* xb = r2 + sC + (size_t)b * 1024 + kg * 8;
#pragma unroll 8
      for (int ks = 0; ks < 32; ++ks) {
        bf16x8 af = *(const bf16x8*)(wpD + ks * 32);
        bf16x8 bf = *(const bf16x8*)(xb + ks * 32);
        acc = __builtin_amdgcn_mfma_f32_16x16x32_bf16(af, bf, acc, 0, 0, 0);
      }
      if (lane < 16) {   // rows 0,1 live in lanes 0-15, regs 0-1
#pragma unroll
        for (int r = 0; r < 2; ++r) {
          int o = nb * 2 + r;
          float v = tanhf(acc[r]);
          cstoreh(&r0[sN + (size_t)b * 1024 + o], f2bf(v));
          houts[((size_t)t * 64 + b) * 512 + o] = v;
        }
      }
    }
    if (t < TT - 1) gbar(cnt, go, gb + 4);
  }
}

// ---------------------------------------------------------------------------
extern "C" void kernel_launch(void* const* d_in, const int* in_sizes, int n_in,
                              void* d_out, int out_size, void* d_ws, size_t ws_size,
                              hipStream_t stream) {
  const int*   src_tokens = (const int*)d_in[0];
  const int*   dst        = (const int*)d_in[2];
  const float* emb_in     = (const float*)d_in[3];
  const float* emb_out    = (const float*)d_in[4];
  const float* enc_w_ih0  = (const float*)d_in[5];
  const float* enc_w_ih1  = (const float*)d_in[6];
  const float* enc_w_hh   = (const float*)d_in[7];
  const float* enc_b_ih   = (const float*)d_in[8];
  const float* enc_b_hh   = (const float*)d_in[9];
  const float* dec_w_ih0  = (const float*)d_in[10];
  const float* dec_w_hh0  = (const float*)d_in[11];
  const float* dec_b_ih0  = (const float*)d_in[12];
  const float* dec_b_hh0  = (const float*)d_in[13];
  const float* dec_w_ih1  = (const float*)d_in[14];
  const float* dec_w_hh1  = (const float*)d_in[15];
  const float* dec_b_ih1  = (const float*)d_in[16];
  const float* dec_b_hh1  = (const float*)d_in[17];
  const float* attn_w     = (const float*)d_in[18];
  const float* pred_w     = (const float*)d_in[19];
  const float* pred_b     = (const float*)d_in[20];
  float* out = (float*)d_out;

  float* ws     = (float*)d_ws;
  float* bufA   = ws;                   // 4,194,304 f
  float* GT     = ws + 4194304;         // 16,777,216 f
  float* encOut = ws + 20971520;        // 4,194,304 f ([b][s][h])
  ushort_t* r0   = (ushort_t*)(ws + 25165824);  // 129*64*1024 bf16
  ushort_t* r1   = (ushort_t*)(ws + 29392896);
  ushort_t* r2   = (ushort_t*)(ws + 33619968);  // 128 slots
  ushort_t* ringE= (ushort_t*)(ws + 37814272);  // 129*2*64*256 bf16
  float* c0T    = ws + 39927808;        // 32,768
  float* c1T    = ws + 39960576;        // 32,768
  // sync: per persist dispatch: go[256*16] (4096 u) + cnt[512*16] (8192 u)
  unsigned* goA  = (unsigned*)(ws + 39993344);
  unsigned* cntA = goA + 4096;
  unsigned* goB  = goA + 12288;
  unsigned* cntB = goA + 16384;
  unsigned* goC  = goA + 24576;
  unsigned* cntC = goA + 28672;
  float* houts  = bufA;

  hipMemsetAsync(goA, 0, 36864 * sizeof(unsigned), stream);
  hipMemsetAsync(r0, 0, 65536 * sizeof(ushort_t), stream);     // slot 0
  hipMemsetAsync(r1, 0, 65536 * sizeof(ushort_t), stream);     // slot 0
  hipMemsetAsync(ringE, 0, 32768 * sizeof(ushort_t), stream);  // slot 0

  // ---- Encoder ----
  k_embed<<<dim3(8192), 128, 0, stream>>>(emb_in, src_tokens, bufA, SS);
  k_gemm<1><<<dim3(16, 64), 256, 0, stream>>>(bufA, 512, enc_w_ih0, 512, 0,
                                              enc_b_ih, enc_b_hh, GT, 2048, 512);
  enc_persist<0><<<dim3(NBLK), 256, 0, stream>>>(GT, enc_w_hh, ringE, bufA,
                                                 r0, c0T, cntA, goA);
  k_gemm<1><<<dim3(16, 64), 256, 0, stream>>>(bufA, 512, enc_w_ih1, 512, 0,
                                              enc_b_ih + 2048, enc_b_hh + 2048, GT, 2048, 512);
  enc_persist<1><<<dim3(NBLK), 256, 0, stream>>>(GT, enc_w_hh + 524288, ringE,
                                                 encOut, r1, c1T, cntB, goB);

  // ---- Decoder precompute (emb part of cell0 gates) ----
  k_embed<<<dim3(8192), 128, 0, stream>>>(emb_out, dst, bufA, TT);
  k_gemm<1><<<dim3(16, 64), 256, 0, stream>>>(bufA, 512, dec_w_ih0, 1024, 0,
                                              dec_b_ih0, dec_b_hh0, GT, 2048, 512);

  // ---- Decoder (persistent, MFMA) ----
  dec_persist<<<dim3(NBLK), 256, 0, stream>>>(
      GT, dec_w_ih0, dec_w_hh0, dec_w_ih1, dec_w_hh1, dec_b_ih1, dec_b_hh1,
      attn_w, encOut, src_tokens, c0T, c1T, r0, r1, r2, houts, cntC, goC);

  // ---- Final projection straight to [B][OUT][T] ----
  k_gemm<2><<<dim3(4, 64), 256, 0, stream>>>(houts, 512, pred_w, 512, 0,
                                             pred_b, nullptr, out, 128, 512);
}

// Round 10
// 5648.285 us; speedup vs baseline: 1.2276x; 1.2276x over previous
//
#include <hip/hip_runtime.h>
#include <hip/hip_bf16.h>

#define SS 128
#define TT 128
#define NBLK 256
#define FSTRIDE 16   // one flag per 64B cacheline

typedef __attribute__((ext_vector_type(8))) short bf16x8;
typedef __attribute__((ext_vector_type(4))) float f32x4;
typedef unsigned short ushort_t;

__device__ __forceinline__ float sigf(float x) { return 1.f / (1.f + __expf(-x)); }

__device__ __forceinline__ ushort_t f2bf(float f) {   // RNE f32 -> bf16
  unsigned b = __builtin_bit_cast(unsigned, f);
  return (ushort_t)((b + 0x7FFFu + ((b >> 16) & 1u)) >> 16);
}
__device__ __forceinline__ float bf2f(ushort_t u) {
  return __builtin_bit_cast(float, (unsigned)u << 16);
}

// Write-through coherent bf16 store (to MALL): cross-block producers.
__device__ __forceinline__ void cstoreh(ushort_t* p, ushort_t v) {
  __hip_atomic_store(p, v, __ATOMIC_RELAXED, __HIP_MEMORY_SCOPE_AGENT);
}

// ---------------------------------------------------------------------------
// R8 master-relay barrier (best measured): per-block arrival lines polled by
// block 0's 256 threads; per-block go lines (1 writer + 1 reader each).
// R9's fetch_add variant REGRESSED (256 same-line RMWs serialize ~6us) - reverted.
__device__ __forceinline__ void gbar(unsigned* flags, unsigned gen) {
  __syncthreads();
  int tid = threadIdx.x;
  unsigned* arr = flags;
  unsigned* go  = flags + NBLK * FSTRIDE;
  if (blockIdx.x == 0) {
    if (tid > 0) {
      int guard = 0;
      while (__hip_atomic_load(&arr[tid * FSTRIDE], __ATOMIC_RELAXED,
                               __HIP_MEMORY_SCOPE_AGENT) < gen &&
             ++guard < (1 << 20))
        __builtin_amdgcn_s_sleep(1);
    }
    __syncthreads();
    __hip_atomic_store(&go[tid * FSTRIDE], gen, __ATOMIC_RELAXED,
                       __HIP_MEMORY_SCOPE_AGENT);
  } else {
    if (tid == 0) {
      asm volatile("s_waitcnt vmcnt(0)" ::: "memory");
      __hip_atomic_store(&arr[blockIdx.x * FSTRIDE], gen, __ATOMIC_RELAXED,
                         __HIP_MEMORY_SCOPE_AGENT);
      int guard = 0;
      while (__hip_atomic_load(&go[blockIdx.x * FSTRIDE], __ATOMIC_RELAXED,
                               __HIP_MEMORY_SCOPE_AGENT) < gen &&
             ++guard < (1 << 20))
        __builtin_amdgcn_s_sleep(1);
    }
    __syncthreads();
  }
  asm volatile("" ::: "memory");
}

// ---------------------------------------------------------------------------
// Embedding gather -> bf16 [seq*64][512]
__global__ void k_embed_bf(const float* __restrict__ emb, const int* __restrict__ toks,
                           ushort_t* __restrict__ out, int seqlen) {
  int s = blockIdx.x >> 6, b = blockIdx.x & 63;
  int tok = toks[b * seqlen + s];
  float4 v = ((const float4*)(emb + (size_t)tok * 512))[threadIdx.x];
  unsigned lo = (unsigned)f2bf(v.x) | ((unsigned)f2bf(v.y) << 16);
  unsigned hi = (unsigned)f2bf(v.z) | ((unsigned)f2bf(v.w) << 16);
  uint2 pk = {lo, hi};
  *(uint2*)&out[(size_t)blockIdx.x * 512 + threadIdx.x * 4] = pk;
}

// Cast gate weights to bf16: wBF[0]=enc_w_ih0[2048][512], wBF[1]=enc_w_ih1,
// wBF[2]=dec_w_ih0[:, 0:512] (emb part).
__global__ void k_castw(const float* __restrict__ s0, const float* __restrict__ s1,
                        const float* __restrict__ s2, ushort_t* __restrict__ wBF) {
  int row = blockIdx.x, which = blockIdx.y;
  const float* src = (which == 0) ? s0 + (size_t)row * 512
                   : (which == 1) ? s1 + (size_t)row * 512
                                  : s2 + (size_t)row * 1024;
  float4 v = ((const float4*)src)[threadIdx.x];
  unsigned lo = (unsigned)f2bf(v.x) | ((unsigned)f2bf(v.y) << 16);
  unsigned hi = (unsigned)f2bf(v.z) | ((unsigned)f2bf(v.w) << 16);
  uint2 pk = {lo, hi};
  *(uint2*)&wBF[((size_t)which * 2048 + row) * 512 + threadIdx.x * 4] = pk;
}

// ---------------------------------------------------------------------------
// bf16 MFMA GEMM for input-gate precompute:
// GT[(m>>6)][n][m&63] = X[m][:]·W[n][:] + b1[n] + b2[n],  M=8192,N=2048,K=512.
// Block tile 128m x 128n, BK=64; 4 waves: wv>>1 = m-half, wv&1 = n-half.
// Frags (verified convention, R8): A lane l: row=l&15, k=(l>>4)*8+i;
// D lane l reg r: row=(l>>4)*4+r, col=l&15.
__global__ __launch_bounds__(256) void gemm_bf(
    const ushort_t* __restrict__ X, const ushort_t* __restrict__ W,
    const float* __restrict__ b1, const float* __restrict__ b2,
    float* __restrict__ GT) {
  __shared__ ushort_t Xs[128 * 72];   // +8 pad: 2-way bank aliasing (free)
  __shared__ ushort_t Ws[128 * 72];
  __shared__ float sbias[128];
  int n0 = blockIdx.x * 128, m0 = blockIdx.y * 128;
  int tid = threadIdx.x;
  int lane = tid & 63;
  int wv = __builtin_amdgcn_readfirstlane(tid >> 6);
  int h_m = (wv >> 1) * 64, h_n = (wv & 1) * 64;
  int l16 = lane & 15, l4 = (lane >> 4) * 4, k8 = (lane >> 4) * 8;
  if (tid < 128) sbias[tid] = b1[n0 + tid] + b2[n0 + tid];
  f32x4 acc[4][4] = {};
  int lrow = tid >> 1, lhf = (tid & 1) * 32;
  for (int k0 = 0; k0 < 512; k0 += 64) {
    __syncthreads();
    const ushort_t* xs = X + (size_t)(m0 + lrow) * 512 + k0 + lhf;
    const ushort_t* wsrc = W + (size_t)(n0 + lrow) * 512 + k0 + lhf;
#pragma unroll
    for (int q = 0; q < 4; ++q) {
      *(bf16x8*)&Xs[lrow * 72 + lhf + q * 8] = *(const bf16x8*)(xs + q * 8);
      *(bf16x8*)&Ws[lrow * 72 + lhf + q * 8] = *(const bf16x8*)(wsrc + q * 8);
    }
    __syncthreads();
#pragma unroll
    for (int kk = 0; kk < 2; ++kk) {
#pragma unroll
      for (int mt = 0; mt < 4; ++mt) {
        bf16x8 af = *(const bf16x8*)&Xs[(h_m + mt * 16 + l16) * 72 + kk * 32 + k8];
#pragma unroll
        for (int nt = 0; nt < 4; ++nt) {
          bf16x8 bf = *(const bf16x8*)&Ws[(h_n + nt * 16 + l16) * 72 + kk * 32 + k8];
          acc[mt][nt] = __builtin_amdgcn_mfma_f32_16x16x32_bf16(af, bf, acc[mt][nt], 0, 0, 0);
        }
      }
    }
  }
  int s = (m0 + h_m) >> 6;
#pragma unroll
  for (int nt = 0; nt < 4; ++nt) {
    int n = n0 + h_n + nt * 16 + l16;
    float bias = sbias[h_n + nt * 16 + l16];
#pragma unroll
    for (int mt = 0; mt < 4; ++mt) {
      f32x4 v = acc[mt][nt];
      v[0] += bias; v[1] += bias; v[2] += bias; v[3] += bias;
      *(f32x4*)&GT[((size_t)s * 2048 + n) * 64 + mt * 16 + l4] = v;
    }
  }
}

// ---------------------------------------------------------------------------
// fp32 GEMM, final projection only: out[((m&63)*512+n)*128+(m>>6)].
__global__ __launch_bounds__(256) void k_gemm2(
    const float* __restrict__ X, const float* __restrict__ W,
    const float* __restrict__ b1, float* __restrict__ C, int K) {
  __shared__ float Xs[16][132];
  __shared__ float Ws[16][132];
  int m0 = blockIdx.y * 128, n0 = blockIdx.x * 128;
  int tx = threadIdx.x & 15, ty = threadIdx.x >> 4;
  float acc[8][8] = {};
  for (int k0 = 0; k0 < K; k0 += 16) {
    __syncthreads();
#pragma unroll
    for (int j = 0; j < 2; ++j) {
      int f4 = threadIdx.x + j * 256;
      int row = f4 >> 2, kc = (f4 & 3) * 4;
      float4 xv = *(const float4*)&X[(size_t)(m0 + row) * 512 + k0 + kc];
      Xs[kc + 0][row] = xv.x; Xs[kc + 1][row] = xv.y;
      Xs[kc + 2][row] = xv.z; Xs[kc + 3][row] = xv.w;
      float4 wv = *(const float4*)&W[(size_t)(n0 + row) * 512 + k0 + kc];
      Ws[kc + 0][row] = wv.x; Ws[kc + 1][row] = wv.y;
      Ws[kc + 2][row] = wv.z; Ws[kc + 3][row] = wv.w;
    }
    __syncthreads();
#pragma unroll
    for (int kk = 0; kk < 16; ++kk) {
      float a[8], w[8];
      *(float4*)&a[0] = *(const float4*)&Xs[kk][ty * 8];
      *(float4*)&a[4] = *(const float4*)&Xs[kk][ty * 8 + 4];
      *(float4*)&w[0] = *(const float4*)&Ws[kk][tx * 8];
      *(float4*)&w[4] = *(const float4*)&Ws[kk][tx * 8 + 4];
#pragma unroll
      for (int i = 0; i < 8; ++i)
#pragma unroll
        for (int j = 0; j < 8; ++j)
          acc[i][j] += a[i] * w[j];
    }
  }
  for (int i = 0; i < 8; ++i) {
    int m = m0 + ty * 8 + i;
#pragma unroll
    for (int j = 0; j < 8; ++j) {
      int n = n0 + tx * 8 + j;
      C[((size_t)(m & 63) * 512 + n) * 128 + (m >> 6)] = acc[i][j] + b1[n];
    }
  }
}

// ---------------------------------------------------------------------------
// Persistent encoder layer: K=256, ring ringE[129][2][64][256] bf16.
// LOUT=0: lout is ushort bf16 [8192][512] (feeds layer-1 MFMA GEMM).
// LOUT=1: lout is float [64][128][512] (encOut for attention).
template<int LOUT>
__global__ __launch_bounds__(256, 1) void enc_persist(
    const float* __restrict__ GT,     // [128][2048][64] input gates fp32
    const float* __restrict__ whh,    // [2][1024][256] this layer fp32
    ushort_t* __restrict__ ringE,     // [129][2][64][256] bf16
    void* __restrict__ lout,
    ushort_t* __restrict__ hFin,      // dec ring slot0 [64][1024]; 512+d*256+hu
    float* __restrict__ cFin,         // [512][64] fp32
    unsigned* bar) {
  int nb = blockIdx.x;
  int d = nb >> 7, nbL = nb & 127;
  int tid = threadIdx.x;
  int lane = tid & 63;
  int wv = __builtin_amdgcn_readfirstlane(tid >> 6);
  int l16 = lane & 15, kg = lane >> 4;
  __shared__ ushort_t wE[16 * 264];

  for (int idx = tid; idx < 16 * 256; idx += 256) {
    int m = idx >> 8, k = idx & 255;
    float v = 0.f;
    if (m < 8)
      v = whh[(size_t)d * 262144 +
              (size_t)((m & 3) * 256 + nbL + 128 * (m >> 2)) * 256 + k];
    wE[m * 264 + k] = f2bf(v);
  }
  __syncthreads();

  int b = wv * 16 + l16;
  int hu = nbL + 128 * kg;            // epilogue lanes (<32)
  float creg = 0.f;
  const ushort_t* wp = wE + l16 * 264 + kg * 8;

  for (int t = 0; t < SS; ++t) {
    int s = d ? (SS - 1 - t) : t;
    float gi[4];
    if (lane < 32) {                  // issue during MFMA latency
#pragma unroll
      for (int r = 0; r < 4; ++r)
        gi[r] = GT[((size_t)s * 2048 + d * 1024 + r * 256 + hu) * 64 + b];
    }
    f32x4 acc = {0.f, 0.f, 0.f, 0.f};
    const ushort_t* xb = ringE + ((size_t)(t * 2 + d) * 64 + b) * 256 + kg * 8;
#pragma unroll
    for (int ks = 0; ks < 8; ++ks) {
      bf16x8 af = *(const bf16x8*)(wp + ks * 32);
      bf16x8 bf = *(const bf16x8*)(xb + ks * 32);
      acc = __builtin_amdgcn_mfma_f32_16x16x32_bf16(af, bf, acc, 0, 0, 0);
    }
    if (lane < 32) {
      float g4[4];
#pragma unroll
      for (int r = 0; r < 4; ++r) g4[r] = acc[r] + gi[r];
      float ig = sigf(g4[0]), fg = sigf(g4[1]), gg = tanhf(g4[2]), og = sigf(g4[3]);
      creg = fg * creg + ig * gg;
      float hn = og * tanhf(creg);
      cstoreh(&ringE[((size_t)((t + 1) * 2 + d) * 64 + b) * 256 + hu], f2bf(hn));
      if (LOUT == 0)
        ((ushort_t*)lout)[((size_t)s * 64 + b) * 512 + d * 256 + hu] = f2bf(hn);
      else
        ((float*)lout)[(size_t)b * 65536 + (size_t)s * 512 + d * 256 + hu] = hn;
      if (t == SS - 1) {
        hFin[(size_t)b * 1024 + 512 + d * 256 + hu] = f2bf(hn);
        cFin[(d * 256 + hu) * 64 + b] = creg;
      }
    }
    if (t < SS - 1) gbar(bar, (unsigned)(t + 1));
  }
}

// ---------------------------------------------------------------------------
// Persistent decoder: 128 steps x {cell0, cell1, attention, outproj}.
// bf16 rings [slot][64 b][1024 k]: r0=[feed|h0], r1=[h0|h1], r2=[ctx|h1].
__global__ __launch_bounds__(256, 1) void dec_persist(
    const float* __restrict__ GdT,    // [128][2048][64] emb gates fp32
    const float* __restrict__ w_ih0, const float* __restrict__ w_hh0,
    const float* __restrict__ w_ih1, const float* __restrict__ w_hh1,
    const float* __restrict__ b_ih1, const float* __restrict__ b_hh1,
    const float* __restrict__ attn_w,
    const float* __restrict__ enc_out,   // [64][128][512] fp32
    const int* __restrict__ src_tokens,
    const float* __restrict__ c0T, const float* __restrict__ c1T,  // [512][64]
    ushort_t* __restrict__ r0, ushort_t* __restrict__ r1,
    ushort_t* __restrict__ r2,
    float* __restrict__ houts,        // [8192][512] fp32
    unsigned* bar) {
  int nb = blockIdx.x;
  int tid = threadIdx.x;
  int lane = tid & 63;
  int wv = __builtin_amdgcn_readfirstlane(tid >> 6);
  int l16 = lane & 15, kg = lane >> 4;
  __shared__ ushort_t wAl[16 * 1032];
  __shared__ ushort_t wBl[16 * 1032];
  __shared__ ushort_t wDl[16 * 1032];
  __shared__ float h1s[512];
  __shared__ float sc[128];

  // ---- stage bf16 weights (once). Rows 0-3: gates hu=nb; 4-7: hu=nb+256.
  for (int idx = tid; idx < 16384; idx += 256) {
    int m = idx >> 10, k = idx & 1023;
    float va = 0.f, vb = 0.f, vd = 0.f;
    if (m < 8) {
      int row = (m & 3) * 512 + nb + 256 * (m >> 2);
      va = (k < 512) ? w_ih0[(size_t)row * 1024 + 512 + k]
                     : w_hh0[(size_t)row * 512 + (k - 512)];
      vb = (k < 512) ? w_ih1[(size_t)row * 512 + k]
                     : w_hh1[(size_t)row * 512 + (k - 512)];
    }
    if (m < 2) vd = attn_w[(size_t)(nb * 2 + m) * 1024 + k];
    wAl[m * 1032 + k] = f2bf(va);
    wBl[m * 1032 + k] = f2bf(vb);
    wDl[m * 1032 + k] = f2bf(vd);
  }
  __syncthreads();

  int b = wv * 16 + l16;
  int hu = nb + 256 * kg;             // epilogue lanes (<32)
  float c0r = 0.f, c1r = 0.f, bias1[4] = {0.f, 0.f, 0.f, 0.f};
  if (lane < 32) {
    c0r = c0T[hu * 64 + b];
    c1r = c1T[hu * 64 + b];
#pragma unroll
    for (int r = 0; r < 4; ++r)
      bias1[r] = b_ih1[r * 512 + hu] + b_hh1[r * 512 + hu];
  }
  const ushort_t* wpA = wAl + l16 * 1032 + kg * 8;
  const ushort_t* wpB = wBl + l16 * 1032 + kg * 8;
  const ushort_t* wpD = wDl + l16 * 1032 + kg * 8;

  for (int t = 0; t < TT; ++t) {
    unsigned gb = (unsigned)(t * 4);
    size_t sC = (size_t)t * 65536, sN = (size_t)(t + 1) * 65536;
    // ---- A: cell0 (x = [feed(t)|h0(t)] = r0 slot t) ----
    {
      float giA[4];
      if (lane < 32) {
#pragma unroll
        for (int r = 0; r < 4; ++r)
          giA[r] = GdT[((size_t)t * 2048 + r * 512 + hu) * 64 + b];
      }
      f32x4 acc = {0.f, 0.f, 0.f, 0.f};
      const ushort_t* xb = r0 + sC + (size_t)b * 1024 + kg * 8;
#pragma unroll 8
      for (int ks = 0; ks < 32; ++ks) {
        bf16x8 af = *(const bf16x8*)(wpA + ks * 32);
        bf16x8 bf = *(const bf16x8*)(xb + ks * 32);
        acc = __builtin_amdgcn_mfma_f32_16x16x32_bf16(af, bf, acc, 0, 0, 0);
      }
      if (lane < 32) {
        float g4[4];
#pragma unroll
        for (int r = 0; r < 4; ++r) g4[r] = acc[r] + giA[r];
        float ig = sigf(g4[0]), fg = sigf(g4[1]), gg = tanhf(g4[2]), og = sigf(g4[3]);
        c0r = fg * c0r + ig * gg;
        float hn = og * tanhf(c0r);
        ushort_t hb = f2bf(hn);
        cstoreh(&r0[sN + (size_t)b * 1024 + 512 + hu], hb);
        cstoreh(&r1[sC + (size_t)b * 1024 + hu], hb);
      }
    }
    gbar(bar, gb + 1);
    // ---- B: cell1 (x = [h0(t)|h1(t-1)] = r1 slot t) ----
    {
      f32x4 acc = {0.f, 0.f, 0.f, 0.f};
      const ushort_t* xb = r1 + sC + (size_t)b * 1024 + kg * 8;
#pragma unroll 8
      for (int ks = 0; ks < 32; ++ks) {
        bf16x8 af = *(const bf16x8*)(wpB + ks * 32);
        bf16x8 bf = *(const bf16x8*)(xb + ks * 32);
        acc = __builtin_amdgcn_mfma_f32_16x16x32_bf16(af, bf, acc, 0, 0, 0);
      }
      if (lane < 32) {
        float g4[4];
#pragma unroll
        for (int r = 0; r < 4; ++r) g4[r] = acc[r] + bias1[r];
        float ig = sigf(g4[0]), fg = sigf(g4[1]), gg = tanhf(g4[2]), og = sigf(g4[3]);
        c1r = fg * c1r + ig * gg;
        float hn = og * tanhf(c1r);
        ushort_t hb = f2bf(hn);
        cstoreh(&r1[sN + (size_t)b * 1024 + 512 + hu], hb);
        cstoreh(&r2[sC + (size_t)b * 1024 + 512 + hu], hb);
      }
    }
    gbar(bar, gb + 2);
    // ---- C: attention (blocks 0..63, one per batch; fp32) ----
    if (nb < 64) {
      const ushort_t* h1b = r1 + sN + (size_t)nb * 1024 + 512;
      const float* eb = enc_out + (size_t)nb * 65536;
      for (int i = tid; i < 512; i += 256) h1s[i] = bf2f(h1b[i]);
      __syncthreads();
      {
        int s2 = tid >> 1, half = tid & 1;
        const float* er = eb + (size_t)s2 * 512 + half * 256;
        const float* hh = h1s + half * 256;
        float a = 0.f;
#pragma unroll 8
        for (int k = 0; k < 256; k += 4) {
          float4 ev = *(const float4*)&er[k];
          a += ev.x * hh[k] + ev.y * hh[k + 1] + ev.z * hh[k + 2] + ev.w * hh[k + 3];
        }
        a += __shfl_xor(a, 1);
        if (!half) sc[s2] = (src_tokens[nb * SS + s2] == 0) ? -1e30f : a;
      }
      __syncthreads();
      if (tid < 64) {
        float m = fmaxf(sc[tid], sc[tid + 64]);
        for (int off = 32; off; off >>= 1) m = fmaxf(m, __shfl_xor(m, off));
        float e0 = __expf(sc[tid] - m), e1 = __expf(sc[tid + 64] - m);
        float ssum = e0 + e1;
        for (int off = 32; off; off >>= 1) ssum += __shfl_xor(ssum, off);
        float inv = 1.f / ssum;
        sc[tid] = e0 * inv; sc[tid + 64] = e1 * inv;
      }
      __syncthreads();
      float a0 = 0.f, a1 = 0.f;
      for (int s2 = 0; s2 < 128; ++s2) {
        float p_ = sc[s2];
        const float* er = eb + (size_t)s2 * 512;
        a0 += p_ * er[tid];
        a1 += p_ * er[tid + 256];
      }
      cstoreh(&r2[sC + (size_t)nb * 1024 + tid], f2bf(a0));
      cstoreh(&r2[sC + (size_t)nb * 1024 + tid + 256], f2bf(a1));
    }
    gbar(bar, gb + 3);
    // ---- D: outproj tanh([ctx|h1] @ attn_w^T) -> feed + houts ----
    {
      f32x4 acc = {0.f, 0.f, 0.f, 0.f};
      const ushort_t* xb = r2 + sC + (size_t)b * 1024 + kg * 8;
#pragma unroll 8
      for (int ks = 0; ks < 32; ++ks) {
        bf16x8 af = *(const bf16x8*)(wpD + ks * 32);
        bf16x8 bf = *(const bf16x8*)(xb + ks * 32);
        acc = __builtin_amdgcn_mfma_f32_16x16x32_bf16(af, bf, acc, 0, 0, 0);
      }
      if (lane < 16) {   // rows 0,1 live in lanes 0-15, regs 0-1
#pragma unroll
        for (int r = 0; r < 2; ++r) {
          int o = nb * 2 + r;
          float v = tanhf(acc[r]);
          cstoreh(&r0[sN + (size_t)b * 1024 + o], f2bf(v));
          houts[((size_t)t * 64 + b) * 512 + o] = v;
        }
      }
    }
    if (t < TT - 1) gbar(bar, gb + 4);
  }
}

// ---------------------------------------------------------------------------
extern "C" void kernel_launch(void* const* d_in, const int* in_sizes, int n_in,
                              void* d_out, int out_size, void* d_ws, size_t ws_size,
                              hipStream_t stream) {
  const int*   src_tokens = (const int*)d_in[0];
  const int*   dst        = (const int*)d_in[2];
  const float* emb_in     = (const float*)d_in[3];
  const float* emb_out    = (const float*)d_in[4];
  const float* enc_w_ih0  = (const float*)d_in[5];
  const float* enc_w_ih1  = (const float*)d_in[6];
  const float* enc_w_hh   = (const float*)d_in[7];
  const float* enc_b_ih   = (const float*)d_in[8];
  const float* enc_b_hh   = (const float*)d_in[9];
  const float* dec_w_ih0  = (const float*)d_in[10];
  const float* dec_w_hh0  = (const float*)d_in[11];
  const float* dec_b_ih0  = (const float*)d_in[12];
  const float* dec_b_hh0  = (const float*)d_in[13];
  const float* dec_w_ih1  = (const float*)d_in[14];
  const float* dec_w_hh1  = (const float*)d_in[15];
  const float* dec_b_ih1  = (const float*)d_in[16];
  const float* dec_b_hh1  = (const float*)d_in[17];
  const float* attn_w     = (const float*)d_in[18];
  const float* pred_w     = (const float*)d_in[19];
  const float* pred_b     = (const float*)d_in[20];
  float* out = (float*)d_out;

  float* ws      = (float*)d_ws;
  float* houts   = ws;                             // 4,194,304 f
  float* GT      = ws + 4194304;                   // 16,777,216 f
  float* encOut  = ws + 20971520;                  // 4,194,304 f ([b][s][h])
  ushort_t* r0   = (ushort_t*)(ws + 25165824);     // 129*64*1024 bf16
  ushort_t* r1   = (ushort_t*)(ws + 29392896);
  ushort_t* r2   = (ushort_t*)(ws + 33619968);     // 128 slots; doubles as wBF pre-dec
  ushort_t* wBF  = r2;                             // [3][2048][512] bf16 (dead before dec)
  ushort_t* ringE= (ushort_t*)(ws + 37814272);     // 129*2*64*256 bf16
  float* c0T     = ws + 39927808;                  // 32,768
  float* c1T     = ws + 39960576;                  // 32,768
  unsigned* barA = (unsigned*)(ws + 39993344);     // 3 x 8192 uints
  unsigned* barB = barA + 8192;
  unsigned* barC = barB + 8192;
  ushort_t* U    = (ushort_t*)(ws + 40017920);     // [8192][512] bf16 staging

  hipMemsetAsync(barA, 0, 3 * 8192 * sizeof(unsigned), stream);
  hipMemsetAsync(r0, 0, 65536 * sizeof(ushort_t), stream);     // slot 0
  hipMemsetAsync(r1, 0, 65536 * sizeof(ushort_t), stream);     // slot 0
  hipMemsetAsync(ringE, 0, 32768 * sizeof(ushort_t), stream);  // slot 0

  // ---- One-time weight cast (wBF aliases r2: dec_persist runs after last use)
  k_castw<<<dim3(2048, 3), 128, 0, stream>>>(enc_w_ih0, enc_w_ih1, dec_w_ih0, wBF);

  // ---- Encoder ----
  k_embed_bf<<<dim3(8192), 128, 0, stream>>>(emb_in, src_tokens, U, SS);
  gemm_bf<<<dim3(16, 64), 256, 0, stream>>>(U, wBF, enc_b_ih, enc_b_hh, GT);
  enc_persist<0><<<dim3(NBLK), 256, 0, stream>>>(GT, enc_w_hh, ringE, U,
                                                 r0, c0T, barA);
  gemm_bf<<<dim3(16, 64), 256, 0, stream>>>(U, wBF + 1048576,
                                            enc_b_ih + 2048, enc_b_hh + 2048, GT);
  enc_persist<1><<<dim3(NBLK), 256, 0, stream>>>(GT, enc_w_hh + 524288, ringE,
                                                 encOut, r1, c1T, barB);

  // ---- Decoder precompute (emb part of cell0 gates) ----
  k_embed_bf<<<dim3(8192), 128, 0, stream>>>(emb_out, dst, U, TT);
  gemm_bf<<<dim3(16, 64), 256, 0, stream>>>(U, wBF + 2097152,
                                            dec_b_ih0, dec_b_hh0, GT);

  // ---- Decoder (persistent, MFMA) ----
  dec_persist<<<dim3(NBLK), 256, 0, stream>>>(
      GT, dec_w_ih0, dec_w_hh0, dec_w_ih1, dec_w_hh1, dec_b_ih1, dec_b_hh1,
      attn_w, encOut, src_tokens, c0T, c1T, r0, r1, r2, houts, barC);

  // ---- Final projection straight to [B][OUT][T] ----
  k_gemm2<<<dim3(4, 64), 256, 0, stream>>>(houts, pred_w, pred_b, out, 512);
}

// Round 11
// 4949.924 us; speedup vs baseline: 1.4008x; 1.1411x over previous
//
#include <hip/hip_runtime.h>
#include <hip/hip_bf16.h>

#define SS 128
#define TT 128
#define NBLK 256
#define FSTRIDE 16   // one flag per 64B cacheline

typedef __attribute__((ext_vector_type(8))) short bf16x8;
typedef __attribute__((ext_vector_type(4))) float f32x4;
typedef unsigned short ushort_t;

__device__ __forceinline__ float sigf(float x) { return 1.f / (1.f + __expf(-x)); }

__device__ __forceinline__ ushort_t f2bf(float f) {   // RNE f32 -> bf16
  unsigned b = __builtin_bit_cast(unsigned, f);
  return (ushort_t)((b + 0x7FFFu + ((b >> 16) & 1u)) >> 16);
}
__device__ __forceinline__ float bf2f(ushort_t u) {
  return __builtin_bit_cast(float, (unsigned)u << 16);
}

// Write-through coherent bf16 store (to MALL): cross-block producers.
__device__ __forceinline__ void cstoreh(ushort_t* p, ushort_t v) {
  __hip_atomic_store(p, v, __ATOMIC_RELAXED, __HIP_MEMORY_SCOPE_AGENT);
}

// Fragment-native ring index: element (k, b) of an x-slot lives at
//   ((k>>5)*256 + b*4 + ((k>>3)&3))*8 + (k&7)
// so a wave's MFMA B-frag load (lane=(l16,kg), iter ks) is a CONTIGUOUS 1KB:
//   byte addr = ks*4096 + wv*1024 + l16*64 + kg*16.  (R10 layout was [b][k]:
//   64 scattered lines per instruction -> L2 queueing was ~6us/phase.)
__device__ __forceinline__ int xidx(int k, int b) {
  return (((k >> 5) * 256 + b * 4 + ((k >> 3) & 3)) << 3) + (k & 7);
}

// ---------------------------------------------------------------------------
// R8 master-relay barrier (best measured; R9 fetch_add variant regressed).
__device__ __forceinline__ void gbar(unsigned* flags, unsigned gen) {
  __syncthreads();
  int tid = threadIdx.x;
  unsigned* arr = flags;
  unsigned* go  = flags + NBLK * FSTRIDE;
  if (blockIdx.x == 0) {
    if (tid > 0) {
      int guard = 0;
      while (__hip_atomic_load(&arr[tid * FSTRIDE], __ATOMIC_RELAXED,
                               __HIP_MEMORY_SCOPE_AGENT) < gen &&
             ++guard < (1 << 20))
        __builtin_amdgcn_s_sleep(1);
    }
    __syncthreads();
    __hip_atomic_store(&go[tid * FSTRIDE], gen, __ATOMIC_RELAXED,
                       __HIP_MEMORY_SCOPE_AGENT);
  } else {
    if (tid == 0) {
      asm volatile("s_waitcnt vmcnt(0)" ::: "memory");
      __hip_atomic_store(&arr[blockIdx.x * FSTRIDE], gen, __ATOMIC_RELAXED,
                         __HIP_MEMORY_SCOPE_AGENT);
      int guard = 0;
      while (__hip_atomic_load(&go[blockIdx.x * FSTRIDE], __ATOMIC_RELAXED,
                               __HIP_MEMORY_SCOPE_AGENT) < gen &&
             ++guard < (1 << 20))
        __builtin_amdgcn_s_sleep(1);
    }
    __syncthreads();
  }
  asm volatile("" ::: "memory");
}

// ---------------------------------------------------------------------------
// Embedding gather -> bf16 [seq*64][512]
__global__ void k_embed_bf(const float* __restrict__ emb, const int* __restrict__ toks,
                           ushort_t* __restrict__ out, int seqlen) {
  int s = blockIdx.x >> 6, b = blockIdx.x & 63;
  int tok = toks[b * seqlen + s];
  float4 v = ((const float4*)(emb + (size_t)tok * 512))[threadIdx.x];
  unsigned lo = (unsigned)f2bf(v.x) | ((unsigned)f2bf(v.y) << 16);
  unsigned hi = (unsigned)f2bf(v.z) | ((unsigned)f2bf(v.w) << 16);
  uint2 pk = {lo, hi};
  *(uint2*)&out[(size_t)blockIdx.x * 512 + threadIdx.x * 4] = pk;
}

// Cast gate weights to bf16: wBF[0]=enc_w_ih0[2048][512], wBF[1]=enc_w_ih1,
// wBF[2]=dec_w_ih0[:, 0:512] (emb part).
__global__ void k_castw(const float* __restrict__ s0, const float* __restrict__ s1,
                        const float* __restrict__ s2, ushort_t* __restrict__ wBF) {
  int row = blockIdx.x, which = blockIdx.y;
  const float* src = (which == 0) ? s0 + (size_t)row * 512
                   : (which == 1) ? s1 + (size_t)row * 512
                                  : s2 + (size_t)row * 1024;
  float4 v = ((const float4*)src)[threadIdx.x];
  unsigned lo = (unsigned)f2bf(v.x) | ((unsigned)f2bf(v.y) << 16);
  unsigned hi = (unsigned)f2bf(v.z) | ((unsigned)f2bf(v.w) << 16);
  uint2 pk = {lo, hi};
  *(uint2*)&wBF[((size_t)which * 2048 + row) * 512 + threadIdx.x * 4] = pk;
}

// ---------------------------------------------------------------------------
// bf16 MFMA GEMM for input-gate precompute (R10, unchanged):
// GT[(m>>6)][n][m&63] = X[m][:]·W[n][:] + b1[n] + b2[n],  M=8192,N=2048,K=512.
__global__ __launch_bounds__(256) void gemm_bf(
    const ushort_t* __restrict__ X, const ushort_t* __restrict__ W,
    const float* __restrict__ b1, const float* __restrict__ b2,
    float* __restrict__ GT) {
  __shared__ ushort_t Xs[128 * 72];
  __shared__ ushort_t Ws[128 * 72];
  __shared__ float sbias[128];
  int n0 = blockIdx.x * 128, m0 = blockIdx.y * 128;
  int tid = threadIdx.x;
  int lane = tid & 63;
  int wv = __builtin_amdgcn_readfirstlane(tid >> 6);
  int h_m = (wv >> 1) * 64, h_n = (wv & 1) * 64;
  int l16 = lane & 15, l4 = (lane >> 4) * 4, k8 = (lane >> 4) * 8;
  if (tid < 128) sbias[tid] = b1[n0 + tid] + b2[n0 + tid];
  f32x4 acc[4][4] = {};
  int lrow = tid >> 1, lhf = (tid & 1) * 32;
  for (int k0 = 0; k0 < 512; k0 += 64) {
    __syncthreads();
    const ushort_t* xs = X + (size_t)(m0 + lrow) * 512 + k0 + lhf;
    const ushort_t* wsrc = W + (size_t)(n0 + lrow) * 512 + k0 + lhf;
#pragma unroll
    for (int q = 0; q < 4; ++q) {
      *(bf16x8*)&Xs[lrow * 72 + lhf + q * 8] = *(const bf16x8*)(xs + q * 8);
      *(bf16x8*)&Ws[lrow * 72 + lhf + q * 8] = *(const bf16x8*)(wsrc + q * 8);
    }
    __syncthreads();
#pragma unroll
    for (int kk = 0; kk < 2; ++kk) {
#pragma unroll
      for (int mt = 0; mt < 4; ++mt) {
        bf16x8 af = *(const bf16x8*)&Xs[(h_m + mt * 16 + l16) * 72 + kk * 32 + k8];
#pragma unroll
        for (int nt = 0; nt < 4; ++nt) {
          bf16x8 bf = *(const bf16x8*)&Ws[(h_n + nt * 16 + l16) * 72 + kk * 32 + k8];
          acc[mt][nt] = __builtin_amdgcn_mfma_f32_16x16x32_bf16(af, bf, acc[mt][nt], 0, 0, 0);
        }
      }
    }
  }
  int s = (m0 + h_m) >> 6;
#pragma unroll
  for (int nt = 0; nt < 4; ++nt) {
    int n = n0 + h_n + nt * 16 + l16;
    float bias = sbias[h_n + nt * 16 + l16];
#pragma unroll
    for (int mt = 0; mt < 4; ++mt) {
      f32x4 v = acc[mt][nt];
      v[0] += bias; v[1] += bias; v[2] += bias; v[3] += bias;
      *(f32x4*)&GT[((size_t)s * 2048 + n) * 64 + mt * 16 + l4] = v;
    }
  }
}

// ---------------------------------------------------------------------------
// fp32 GEMM, final projection only: out[((m&63)*512+n)*128+(m>>6)].
__global__ __launch_bounds__(256) void k_gemm2(
    const float* __restrict__ X, const float* __restrict__ W,
    const float* __restrict__ b1, float* __restrict__ C, int K) {
  __shared__ float Xs[16][132];
  __shared__ float Ws[16][132];
  int m0 = blockIdx.y * 128, n0 = blockIdx.x * 128;
  int tx = threadIdx.x & 15, ty = threadIdx.x >> 4;
  float acc[8][8] = {};
  for (int k0 = 0; k0 < K; k0 += 16) {
    __syncthreads();
#pragma unroll
    for (int j = 0; j < 2; ++j) {
      int f4 = threadIdx.x + j * 256;
      int row = f4 >> 2, kc = (f4 & 3) * 4;
      float4 xv = *(const float4*)&X[(size_t)(m0 + row) * 512 + k0 + kc];
      Xs[kc + 0][row] = xv.x; Xs[kc + 1][row] = xv.y;
      Xs[kc + 2][row] = xv.z; Xs[kc + 3][row] = xv.w;
      float4 wv = *(const float4*)&W[(size_t)(n0 + row) * 512 + k0 + kc];
      Ws[kc + 0][row] = wv.x; Ws[kc + 1][row] = wv.y;
      Ws[kc + 2][row] = wv.z; Ws[kc + 3][row] = wv.w;
    }
    __syncthreads();
#pragma unroll
    for (int kk = 0; kk < 16; ++kk) {
      float a[8], w[8];
      *(float4*)&a[0] = *(const float4*)&Xs[kk][ty * 8];
      *(float4*)&a[4] = *(const float4*)&Xs[kk][ty * 8 + 4];
      *(float4*)&w[0] = *(const float4*)&Ws[kk][tx * 8];
      *(float4*)&w[4] = *(const float4*)&Ws[kk][tx * 8 + 4];
#pragma unroll
      for (int i = 0; i < 8; ++i)
#pragma unroll
        for (int j = 0; j < 8; ++j)
          acc[i][j] += a[i] * w[j];
    }
  }
  for (int i = 0; i < 8; ++i) {
    int m = m0 + ty * 8 + i;
#pragma unroll
    for (int j = 0; j < 8; ++j) {
      int n = n0 + tx * 8 + j;
      C[((size_t)(m & 63) * 512 + n) * 128 + (m >> 6)] = acc[i][j] + b1[n];
    }
  }
}

// ---------------------------------------------------------------------------
// Persistent encoder layer: K=256, ring ringE[129][2][frag-native 64x256].
template<int LOUT>
__global__ __launch_bounds__(256, 1) void enc_persist(
    const float* __restrict__ GT,     // [128][2048][64] input gates fp32
    const float* __restrict__ whh,    // [2][1024][256] this layer fp32
    ushort_t* __restrict__ ringE,     // [129][2][16384] bf16 frag-native
    void* __restrict__ lout,
    ushort_t* __restrict__ hFin,      // dec ring slot0 (frag-native [64][1024])
    float* __restrict__ cFin,         // [512][64] fp32
    unsigned* bar) {
  int nb = blockIdx.x;
  int d = nb >> 7, nbL = nb & 127;
  int tid = threadIdx.x;
  int lane = tid & 63;
  int wv = __builtin_amdgcn_readfirstlane(tid >> 6);
  int l16 = lane & 15, kg = lane >> 4;
  __shared__ ushort_t wE[16 * 264];

  for (int idx = tid; idx < 16 * 256; idx += 256) {
    int m = idx >> 8, k = idx & 255;
    float v = 0.f;
    if (m < 8)
      v = whh[(size_t)d * 262144 +
              (size_t)((m & 3) * 256 + nbL + 128 * (m >> 2)) * 256 + k];
    wE[m * 264 + k] = f2bf(v);
  }
  __syncthreads();

  int b = wv * 16 + l16;
  int hu = nbL + 128 * kg;            // epilogue lanes (<32)
  float creg = 0.f;
  const ushort_t* wp = wE + l16 * 264 + kg * 8;

  for (int t = 0; t < SS; ++t) {
    int s = d ? (SS - 1 - t) : t;
    float gi[4];
    if (lane < 32) {                  // issue during MFMA latency
#pragma unroll
      for (int r = 0; r < 4; ++r)
        gi[r] = GT[((size_t)s * 2048 + d * 1024 + r * 256 + hu) * 64 + b];
    }
    f32x4 acc = {0.f, 0.f, 0.f, 0.f};
    // frag-native: wave reads contiguous 1KB per iteration
    const ushort_t* xb = ringE + (size_t)(t * 2 + d) * 16384 +
                         wv * 512 + l16 * 32 + kg * 8;
#pragma unroll
    for (int ks = 0; ks < 8; ++ks) {
      bf16x8 af = *(const bf16x8*)(wp + ks * 32);
      bf16x8 bf = *(const bf16x8*)(xb + ks * 2048);
      acc = __builtin_amdgcn_mfma_f32_16x16x32_bf16(af, bf, acc, 0, 0, 0);
    }
    if (lane < 32) {
      float g4[4];
#pragma unroll
      for (int r = 0; r < 4; ++r) g4[r] = acc[r] + gi[r];
      float ig = sigf(g4[0]), fg = sigf(g4[1]), gg = tanhf(g4[2]), og = sigf(g4[3]);
      creg = fg * creg + ig * gg;
      float hn = og * tanhf(creg);
      cstoreh(&ringE[(size_t)((t + 1) * 2 + d) * 16384 + xidx(hu, b)], f2bf(hn));
      if (LOUT == 0)
        ((ushort_t*)lout)[((size_t)s * 64 + b) * 512 + d * 256 + hu] = f2bf(hn);
      else
        ((float*)lout)[(size_t)b * 65536 + (size_t)s * 512 + d * 256 + hu] = hn;
      if (t == SS - 1) {
        hFin[xidx(512 + d * 256 + hu, b)] = f2bf(hn);
        cFin[(d * 256 + hu) * 64 + b] = creg;
      }
    }
    if (t < SS - 1) gbar(bar, (unsigned)(t + 1));
  }
}

// ---------------------------------------------------------------------------
// Persistent decoder: 128 steps x {cell0, cell1, attention, outproj}.
// bf16 rings [slot][frag-native 64x1024]: r0=[feed|h0], r1=[h0|h1], r2=[ctx|h1].
__global__ __launch_bounds__(256, 1) void dec_persist(
    const float* __restrict__ GdT,    // [128][2048][64] emb gates fp32
    const float* __restrict__ w_ih0, const float* __restrict__ w_hh0,
    const float* __restrict__ w_ih1, const float* __restrict__ w_hh1,
    const float* __restrict__ b_ih1, const float* __restrict__ b_hh1,
    const float* __restrict__ attn_w,
    const float* __restrict__ enc_out,   // [64][128][512] fp32
    const int* __restrict__ src_tokens,
    const float* __restrict__ c0T, const float* __restrict__ c1T,  // [512][64]
    ushort_t* __restrict__ r0, ushort_t* __restrict__ r1,
    ushort_t* __restrict__ r2,
    float* __restrict__ houts,        // [8192][512] fp32
    unsigned* bar) {
  int nb = blockIdx.x;
  int tid = threadIdx.x;
  int lane = tid & 63;
  int wv = __builtin_amdgcn_readfirstlane(tid >> 6);
  int l16 = lane & 15, kg = lane >> 4;
  __shared__ ushort_t wAl[16 * 1032];
  __shared__ ushort_t wBl[16 * 1032];
  __shared__ ushort_t wDl[16 * 1032];
  __shared__ float h1s[512];
  __shared__ float sc[128];

  // ---- stage bf16 weights (once). Rows 0-3: gates hu=nb; 4-7: hu=nb+256.
  for (int idx = tid; idx < 16384; idx += 256) {
    int m = idx >> 10, k = idx & 1023;
    float va = 0.f, vb = 0.f, vd = 0.f;
    if (m < 8) {
      int row = (m & 3) * 512 + nb + 256 * (m >> 2);
      va = (k < 512) ? w_ih0[(size_t)row * 1024 + 512 + k]
                     : w_hh0[(size_t)row * 512 + (k - 512)];
      vb = (k < 512) ? w_ih1[(size_t)row * 512 + k]
                     : w_hh1[(size_t)row * 512 + (k - 512)];
    }
    if (m < 2) vd = attn_w[(size_t)(nb * 2 + m) * 1024 + k];
    wAl[m * 1032 + k] = f2bf(va);
    wBl[m * 1032 + k] = f2bf(vb);
    wDl[m * 1032 + k] = f2bf(vd);
  }
  __syncthreads();

  int b = wv * 16 + l16;
  int hu = nb + 256 * kg;             // epilogue lanes (<32)
  float c0r = 0.f, c1r = 0.f, bias1[4] = {0.f, 0.f, 0.f, 0.f};
  if (lane < 32) {
    c0r = c0T[hu * 64 + b];
    c1r = c1T[hu * 64 + b];
#pragma unroll
    for (int r = 0; r < 4; ++r)
      bias1[r] = b_ih1[r * 512 + hu] + b_hh1[r * 512 + hu];
  }
  const ushort_t* wpA = wAl + l16 * 1032 + kg * 8;
  const ushort_t* wpB = wBl + l16 * 1032 + kg * 8;
  const ushort_t* wpD = wDl + l16 * 1032 + kg * 8;
  int fragoff = wv * 512 + l16 * 32 + kg * 8;   // frag-native wave base

  for (int t = 0; t < TT; ++t) {
    unsigned gb = (unsigned)(t * 4);
    size_t sC = (size_t)t * 65536, sN = (size_t)(t + 1) * 65536;
    // ---- A: cell0 (x = [feed(t)|h0(t)] = r0 slot t) ----
    {
      float giA[4];
      if (lane < 32) {
#pragma unroll
        for (int r = 0; r < 4; ++r)
          giA[r] = GdT[((size_t)t * 2048 + r * 512 + hu) * 64 + b];
      }
      f32x4 acc = {0.f, 0.f, 0.f, 0.f};
      const ushort_t* xb = r0 + sC + fragoff;
#pragma unroll 8
      for (int ks = 0; ks < 32; ++ks) {
        bf16x8 af = *(const bf16x8*)(wpA + ks * 32);
        bf16x8 bf = *(const bf16x8*)(xb + ks * 2048);
        acc = __builtin_amdgcn_mfma_f32_16x16x32_bf16(af, bf, acc, 0, 0, 0);
      }
      if (lane < 32) {
        float g4[4];
#pragma unroll
        for (int r = 0; r < 4; ++r) g4[r] = acc[r] + giA[r];
        float ig = sigf(g4[0]), fg = sigf(g4[1]), gg = tanhf(g4[2]), og = sigf(g4[3]);
        c0r = fg * c0r + ig * gg;
        float hn = og * tanhf(c0r);
        ushort_t hb = f2bf(hn);
        cstoreh(&r0[sN + xidx(512 + hu, b)], hb);
        cstoreh(&r1[sC + xidx(hu, b)], hb);
      }
    }
    gbar(bar, gb + 1);
    // ---- B: cell1 (x = [h0(t)|h1(t-1)] = r1 slot t) ----
    {
      f32x4 acc = {0.f, 0.f, 0.f, 0.f};
      const ushort_t* xb = r1 + sC + fragoff;
#pragma unroll 8
      for (int ks = 0; ks < 32; ++ks) {
        bf16x8 af = *(const bf16x8*)(wpB + ks * 32);
        bf16x8 bf = *(const bf16x8*)(xb + ks * 2048);
        acc = __builtin_amdgcn_mfma_f32_16x16x32_bf16(af, bf, acc, 0, 0, 0);
      }
      if (lane < 32) {
        float g4[4];
#pragma unroll
        for (int r = 0; r < 4; ++r) g4[r] = acc[r] + bias1[r];
        float ig = sigf(g4[0]), fg = sigf(g4[1]), gg = tanhf(g4[2]), og = sigf(g4[3]);
        c1r = fg * c1r + ig * gg;
        float hn = og * tanhf(c1r);
        ushort_t hb = f2bf(hn);
        cstoreh(&r1[sN + xidx(512 + hu, b)], hb);
        cstoreh(&r2[sC + xidx(512 + hu, b)], hb);
      }
    }
    gbar(bar, gb + 2);
    // ---- C: attention (blocks 0..63, one per batch; fp32) ----
    if (nb < 64) {
      const float* eb = enc_out + (size_t)nb * 65536;
      for (int i = tid; i < 512; i += 256)
        h1s[i] = bf2f(r1[sN + xidx(512 + i, nb)]);
      __syncthreads();
      {
        int s2 = tid >> 1, half = tid & 1;
        const float* er = eb + (size_t)s2 * 512 + half * 256;
        const float* hh = h1s + half * 256;
        float a = 0.f;
#pragma unroll 8
        for (int k = 0; k < 256; k += 4) {
          float4 ev = *(const float4*)&er[k];
          a += ev.x * hh[k] + ev.y * hh[k + 1] + ev.z * hh[k + 2] + ev.w * hh[k + 3];
        }
        a += __shfl_xor(a, 1);
        if (!half) sc[s2] = (src_tokens[nb * SS + s2] == 0) ? -1e30f : a;
      }
      __syncthreads();
      if (tid < 64) {
        float m = fmaxf(sc[tid], sc[tid + 64]);
        for (int off = 32; off; off >>= 1) m = fmaxf(m, __shfl_xor(m, off));
        float e0 = __expf(sc[tid] - m), e1 = __expf(sc[tid + 64] - m);
        float ssum = e0 + e1;
        for (int off = 32; off; off >>= 1) ssum += __shfl_xor(ssum, off);
        float inv = 1.f / ssum;
        sc[tid] = e0 * inv; sc[tid + 64] = e1 * inv;
      }
      __syncthreads();
      float a0 = 0.f, a1 = 0.f;
      for (int s2 = 0; s2 < 128; ++s2) {
        float p_ = sc[s2];
        const float* er = eb + (size_t)s2 * 512;
        a0 += p_ * er[tid];
        a1 += p_ * er[tid + 256];
      }
      cstoreh(&r2[sC + xidx(tid, nb)], f2bf(a0));
      cstoreh(&r2[sC + xidx(tid + 256, nb)], f2bf(a1));
    }
    gbar(bar, gb + 3);
    // ---- D: outproj tanh([ctx|h1] @ attn_w^T) -> feed + houts ----
    {
      f32x4 acc = {0.f, 0.f, 0.f, 0.f};
      const ushort_t* xb = r2 + sC + fragoff;
#pragma unroll 8
      for (int ks = 0; ks < 32; ++ks) {
        bf16x8 af = *(const bf16x8*)(wpD + ks * 32);
        bf16x8 bf = *(const bf16x8*)(xb + ks * 2048);
        acc = __builtin_amdgcn_mfma_f32_16x16x32_bf16(af, bf, acc, 0, 0, 0);
      }
      if (lane < 16) {   // rows 0,1 live in lanes 0-15, regs 0-1
#pragma unroll
        for (int r = 0; r < 2; ++r) {
          int o = nb * 2 + r;
          float v = tanhf(acc[r]);
          cstoreh(&r0[sN + xidx(o, b)], f2bf(v));
          houts[((size_t)t * 64 + b) * 512 + o] = v;
        }
      }
    }
    if (t < TT - 1) gbar(bar, gb + 4);
  }
}

// ---------------------------------------------------------------------------
extern "C" void kernel_launch(void* const* d_in, const int* in_sizes, int n_in,
                              void* d_out, int out_size, void* d_ws, size_t ws_size,
                              hipStream_t stream) {
  const int*   src_tokens = (const int*)d_in[0];
  const int*   dst        = (const int*)d_in[2];
  const float* emb_in     = (const float*)d_in[3];
  const float* emb_out    = (const float*)d_in[4];
  const float* enc_w_ih0  = (const float*)d_in[5];
  const float* enc_w_ih1  = (const float*)d_in[6];
  const float* enc_w_hh   = (const float*)d_in[7];
  const float* enc_b_ih   = (const float*)d_in[8];
  const float* enc_b_hh   = (const float*)d_in[9];
  const float* dec_w_ih0  = (const float*)d_in[10];
  const float* dec_w_hh0  = (const float*)d_in[11];
  const float* dec_b_ih0  = (const float*)d_in[12];
  const float* dec_b_hh0  = (const float*)d_in[13];
  const float* dec_w_ih1  = (const float*)d_in[14];
  const float* dec_w_hh1  = (const float*)d_in[15];
  const float* dec_b_ih1  = (const float*)d_in[16];
  const float* dec_b_hh1  = (const float*)d_in[17];
  const float* attn_w     = (const float*)d_in[18];
  const float* pred_w     = (const float*)d_in[19];
  const float* pred_b     = (const float*)d_in[20];
  float* out = (float*)d_out;

  float* ws      = (float*)d_ws;
  float* houts   = ws;                             // 4,194,304 f
  float* GT      = ws + 4194304;                   // 16,777,216 f
  float* encOut  = ws + 20971520;                  // 4,194,304 f ([b][s][h])
  ushort_t* r0   = (ushort_t*)(ws + 25165824);     // 129*65536 bf16 frag-native
  ushort_t* r1   = (ushort_t*)(ws + 29392896);
  ushort_t* r2   = (ushort_t*)(ws + 33619968);     // 128 slots; doubles as wBF pre-dec
  ushort_t* wBF  = r2;                             // [3][2048][512] bf16 (dead before dec)
  ushort_t* ringE= (ushort_t*)(ws + 37814272);     // 129*2*16384 bf16
  float* c0T     = ws + 39927808;                  // 32,768
  float* c1T     = ws + 39960576;                  // 32,768
  unsigned* barA = (unsigned*)(ws + 39993344);     // 3 x 8192 uints
  unsigned* barB = barA + 8192;
  unsigned* barC = barB + 8192;
  ushort_t* U    = (ushort_t*)(ws + 40017920);     // [8192][512] bf16 staging

  hipMemsetAsync(barA, 0, 3 * 8192 * sizeof(unsigned), stream);
  hipMemsetAsync(r0, 0, 65536 * sizeof(ushort_t), stream);     // slot 0
  hipMemsetAsync(r1, 0, 65536 * sizeof(ushort_t), stream);     // slot 0
  hipMemsetAsync(ringE, 0, 32768 * sizeof(ushort_t), stream);  // slot 0

  // ---- One-time weight cast (wBF aliases r2: dec_persist runs after last use)
  k_castw<<<dim3(2048, 3), 128, 0, stream>>>(enc_w_ih0, enc_w_ih1, dec_w_ih0, wBF);

  // ---- Encoder ----
  k_embed_bf<<<dim3(8192), 128, 0, stream>>>(emb_in, src_tokens, U, SS);
  gemm_bf<<<dim3(16, 64), 256, 0, stream>>>(U, wBF, enc_b_ih, enc_b_hh, GT);
  enc_persist<0><<<dim3(NBLK), 256, 0, stream>>>(GT, enc_w_hh, ringE, U,
                                                 r0, c0T, barA);
  gemm_bf<<<dim3(16, 64), 256, 0, stream>>>(U, wBF + 1048576,
                                            enc_b_ih + 2048, enc_b_hh + 2048, GT);
  enc_persist<1><<<dim3(NBLK), 256, 0, stream>>>(GT, enc_w_hh + 524288, ringE,
                                                 encOut, r1, c1T, barB);

  // ---- Decoder precompute (emb part of cell0 gates) ----
  k_embed_bf<<<dim3(8192), 128, 0, stream>>>(emb_out, dst, U, TT);
  gemm_bf<<<dim3(16, 64), 256, 0, stream>>>(U, wBF + 2097152,
                                            dec_b_ih0, dec_b_hh0, GT);

  // ---- Decoder (persistent, MFMA, frag-native rings) ----
  dec_persist<<<dim3(NBLK), 256, 0, stream>>>(
      GT, dec_w_ih0, dec_w_hh0, dec_w_ih1, dec_w_hh1, dec_b_ih1, dec_b_hh1,
      attn_w, encOut, src_tokens, c0T, c1T, r0, r1, r2, houts, barC);

  // ---- Final projection straight to [B][OUT][T] ----
  k_gemm2<<<dim3(4, 64), 256, 0, stream>>>(houts, pred_w, pred_b, out, 512);
}

// Round 12
// 4858.368 us; speedup vs baseline: 1.4272x; 1.0188x over previous
//
#include <hip/hip_runtime.h>
#include <hip/hip_bf16.h>

#define SS 128
#define TT 128
#define NBLK 256
#define FSTRIDE 16   // one flag per 64B cacheline

typedef __attribute__((ext_vector_type(8))) short bf16x8;
typedef __attribute__((ext_vector_type(4))) float f32x4;
typedef unsigned short ushort_t;

__device__ __forceinline__ float sigf(float x) { return 1.f / (1.f + __expf(-x)); }

__device__ __forceinline__ ushort_t f2bf(float f) {   // RNE f32 -> bf16
  unsigned b = __builtin_bit_cast(unsigned, f);
  return (ushort_t)((b + 0x7FFFu + ((b >> 16) & 1u)) >> 16);
}
__device__ __forceinline__ float bf2f(ushort_t u) {
  return __builtin_bit_cast(float, (unsigned)u << 16);
}

// Write-through coherent bf16 store (to MALL): cross-block producers.
__device__ __forceinline__ void cstoreh(ushort_t* p, ushort_t v) {
  __hip_atomic_store(p, v, __ATOMIC_RELAXED, __HIP_MEMORY_SCOPE_AGENT);
}

// Fragment-native ring index: element (k, b) of an x-slot lives at
//   ((k>>5)*256 + b*4 + ((k>>3)&3))*8 + (k&7)
// -> wave's MFMA B-frag load (lane=(l16,kg), iter ks) is a CONTIGUOUS 1KB.
__device__ __forceinline__ int xidx(int k, int b) {
  return (((k >> 5) * 256 + b * 4 + ((k >> 3) & 3)) << 3) + (k & 7);
}

// ---------------------------------------------------------------------------
// R8 master-relay barrier (best measured; R9 fetch_add variant regressed).
__device__ __forceinline__ void gbar(unsigned* flags, unsigned gen) {
  __syncthreads();
  int tid = threadIdx.x;
  unsigned* arr = flags;
  unsigned* go  = flags + NBLK * FSTRIDE;
  if (blockIdx.x == 0) {
    if (tid > 0) {
      int guard = 0;
      while (__hip_atomic_load(&arr[tid * FSTRIDE], __ATOMIC_RELAXED,
                               __HIP_MEMORY_SCOPE_AGENT) < gen &&
             ++guard < (1 << 20))
        __builtin_amdgcn_s_sleep(1);
    }
    __syncthreads();
    __hip_atomic_store(&go[tid * FSTRIDE], gen, __ATOMIC_RELAXED,
                       __HIP_MEMORY_SCOPE_AGENT);
  } else {
    if (tid == 0) {
      asm volatile("s_waitcnt vmcnt(0)" ::: "memory");
      __hip_atomic_store(&arr[blockIdx.x * FSTRIDE], gen, __ATOMIC_RELAXED,
                         __HIP_MEMORY_SCOPE_AGENT);
      int guard = 0;
      while (__hip_atomic_load(&go[blockIdx.x * FSTRIDE], __ATOMIC_RELAXED,
                               __HIP_MEMORY_SCOPE_AGENT) < gen &&
             ++guard < (1 << 20))
        __builtin_amdgcn_s_sleep(1);
    }
    __syncthreads();
  }
  asm volatile("" ::: "memory");
}

// ---------------------------------------------------------------------------
// Embedding gather -> bf16 [seq*64][512]
__global__ void k_embed_bf(const float* __restrict__ emb, const int* __restrict__ toks,
                           ushort_t* __restrict__ out, int seqlen) {
  int s = blockIdx.x >> 6, b = blockIdx.x & 63;
  int tok = toks[b * seqlen + s];
  float4 v = ((const float4*)(emb + (size_t)tok * 512))[threadIdx.x];
  unsigned lo = (unsigned)f2bf(v.x) | ((unsigned)f2bf(v.y) << 16);
  unsigned hi = (unsigned)f2bf(v.z) | ((unsigned)f2bf(v.w) << 16);
  uint2 pk = {lo, hi};
  *(uint2*)&out[(size_t)blockIdx.x * 512 + threadIdx.x * 4] = pk;
}

// Cast gate weights to bf16: wBF[0]=enc_w_ih0[2048][512], wBF[1]=enc_w_ih1,
// wBF[2]=dec_w_ih0[:, 0:512] (emb part).
__global__ void k_castw(const float* __restrict__ s0, const float* __restrict__ s1,
                        const float* __restrict__ s2, ushort_t* __restrict__ wBF) {
  int row = blockIdx.x, which = blockIdx.y;
  const float* src = (which == 0) ? s0 + (size_t)row * 512
                   : (which == 1) ? s1 + (size_t)row * 512
                                  : s2 + (size_t)row * 1024;
  float4 v = ((const float4*)src)[threadIdx.x];
  unsigned lo = (unsigned)f2bf(v.x) | ((unsigned)f2bf(v.y) << 16);
  unsigned hi = (unsigned)f2bf(v.z) | ((unsigned)f2bf(v.w) << 16);
  uint2 pk = {lo, hi};
  *(uint2*)&wBF[((size_t)which * 2048 + row) * 512 + threadIdx.x * 4] = pk;
}

// ---------------------------------------------------------------------------
// bf16 MFMA GEMM for input-gate precompute (R10, unchanged):
// GT[(m>>6)][n][m&63] = X[m][:]·W[n][:] + b1[n] + b2[n],  M=8192,N=2048,K=512.
__global__ __launch_bounds__(256) void gemm_bf(
    const ushort_t* __restrict__ X, const ushort_t* __restrict__ W,
    const float* __restrict__ b1, const float* __restrict__ b2,
    float* __restrict__ GT) {
  __shared__ ushort_t Xs[128 * 72];
  __shared__ ushort_t Ws[128 * 72];
  __shared__ float sbias[128];
  int n0 = blockIdx.x * 128, m0 = blockIdx.y * 128;
  int tid = threadIdx.x;
  int lane = tid & 63;
  int wv = __builtin_amdgcn_readfirstlane(tid >> 6);
  int h_m = (wv >> 1) * 64, h_n = (wv & 1) * 64;
  int l16 = lane & 15, l4 = (lane >> 4) * 4, k8 = (lane >> 4) * 8;
  if (tid < 128) sbias[tid] = b1[n0 + tid] + b2[n0 + tid];
  f32x4 acc[4][4] = {};
  int lrow = tid >> 1, lhf = (tid & 1) * 32;
  for (int k0 = 0; k0 < 512; k0 += 64) {
    __syncthreads();
    const ushort_t* xs = X + (size_t)(m0 + lrow) * 512 + k0 + lhf;
    const ushort_t* wsrc = W + (size_t)(n0 + lrow) * 512 + k0 + lhf;
#pragma unroll
    for (int q = 0; q < 4; ++q) {
      *(bf16x8*)&Xs[lrow * 72 + lhf + q * 8] = *(const bf16x8*)(xs + q * 8);
      *(bf16x8*)&Ws[lrow * 72 + lhf + q * 8] = *(const bf16x8*)(wsrc + q * 8);
    }
    __syncthreads();
#pragma unroll
    for (int kk = 0; kk < 2; ++kk) {
#pragma unroll
      for (int mt = 0; mt < 4; ++mt) {
        bf16x8 af = *(const bf16x8*)&Xs[(h_m + mt * 16 + l16) * 72 + kk * 32 + k8];
#pragma unroll
        for (int nt = 0; nt < 4; ++nt) {
          bf16x8 bf = *(const bf16x8*)&Ws[(h_n + nt * 16 + l16) * 72 + kk * 32 + k8];
          acc[mt][nt] = __builtin_amdgcn_mfma_f32_16x16x32_bf16(af, bf, acc[mt][nt], 0, 0, 0);
        }
      }
    }
  }
  int s = (m0 + h_m) >> 6;
#pragma unroll
  for (int nt = 0; nt < 4; ++nt) {
    int n = n0 + h_n + nt * 16 + l16;
    float bias = sbias[h_n + nt * 16 + l16];
#pragma unroll
    for (int mt = 0; mt < 4; ++mt) {
      f32x4 v = acc[mt][nt];
      v[0] += bias; v[1] += bias; v[2] += bias; v[3] += bias;
      *(f32x4*)&GT[((size_t)s * 2048 + n) * 64 + mt * 16 + l4] = v;
    }
  }
}

// ---------------------------------------------------------------------------
// fp32 GEMM, final projection only: out[((m&63)*512+n)*128+(m>>6)].
__global__ __launch_bounds__(256) void k_gemm2(
    const float* __restrict__ X, const float* __restrict__ W,
    const float* __restrict__ b1, float* __restrict__ C, int K) {
  __shared__ float Xs[16][132];
  __shared__ float Ws[16][132];
  int m0 = blockIdx.y * 128, n0 = blockIdx.x * 128;
  int tx = threadIdx.x & 15, ty = threadIdx.x >> 4;
  float acc[8][8] = {};
  for (int k0 = 0; k0 < K; k0 += 16) {
    __syncthreads();
#pragma unroll
    for (int j = 0; j < 2; ++j) {
      int f4 = threadIdx.x + j * 256;
      int row = f4 >> 2, kc = (f4 & 3) * 4;
      float4 xv = *(const float4*)&X[(size_t)(m0 + row) * 512 + k0 + kc];
      Xs[kc + 0][row] = xv.x; Xs[kc + 1][row] = xv.y;
      Xs[kc + 2][row] = xv.z; Xs[kc + 3][row] = xv.w;
      float4 wv = *(const float4*)&W[(size_t)(n0 + row) * 512 + k0 + kc];
      Ws[kc + 0][row] = wv.x; Ws[kc + 1][row] = wv.y;
      Ws[kc + 2][row] = wv.z; Ws[kc + 3][row] = wv.w;
    }
    __syncthreads();
#pragma unroll
    for (int kk = 0; kk < 16; ++kk) {
      float a[8], w[8];
      *(float4*)&a[0] = *(const float4*)&Xs[kk][ty * 8];
      *(float4*)&a[4] = *(const float4*)&Xs[kk][ty * 8 + 4];
      *(float4*)&w[0] = *(const float4*)&Ws[kk][tx * 8];
      *(float4*)&w[4] = *(const float4*)&Ws[kk][tx * 8 + 4];
#pragma unroll
      for (int i = 0; i < 8; ++i)
#pragma unroll
        for (int j = 0; j < 8; ++j)
          acc[i][j] += a[i] * w[j];
    }
  }
  for (int i = 0; i < 8; ++i) {
    int m = m0 + ty * 8 + i;
#pragma unroll
    for (int j = 0; j < 8; ++j) {
      int n = n0 + tx * 8 + j;
      C[((size_t)(m & 63) * 512 + n) * 128 + (m >> 6)] = acc[i][j] + b1[n];
    }
  }
}

// ---------------------------------------------------------------------------
// Persistent encoder layer: K=256, ring ringE[129][2][frag-native 64x256].
template<int LOUT>
__global__ __launch_bounds__(256, 1) void enc_persist(
    const float* __restrict__ GT,     // [128][2048][64] input gates fp32
    const float* __restrict__ whh,    // [2][1024][256] this layer fp32
    ushort_t* __restrict__ ringE,     // [129][2][16384] bf16 frag-native
    void* __restrict__ lout,
    ushort_t* __restrict__ hFin,      // dec ring slot0 (frag-native [64][1024])
    float* __restrict__ cFin,         // [512][64] fp32
    unsigned* bar) {
  int nb = blockIdx.x;
  int d = nb >> 7, nbL = nb & 127;
  int tid = threadIdx.x;
  int lane = tid & 63;
  int wv = __builtin_amdgcn_readfirstlane(tid >> 6);
  int l16 = lane & 15, kg = lane >> 4;
  __shared__ ushort_t wE[16 * 264];

  for (int idx = tid; idx < 16 * 256; idx += 256) {
    int m = idx >> 8, k = idx & 255;
    float v = 0.f;
    if (m < 8)
      v = whh[(size_t)d * 262144 +
              (size_t)((m & 3) * 256 + nbL + 128 * (m >> 2)) * 256 + k];
    wE[m * 264 + k] = f2bf(v);
  }
  __syncthreads();

  int b = wv * 16 + l16;
  int hu = nbL + 128 * kg;            // epilogue lanes (<32)
  float creg = 0.f;
  const ushort_t* wp = wE + l16 * 264 + kg * 8;

  for (int t = 0; t < SS; ++t) {
    int s = d ? (SS - 1 - t) : t;
    // ---- issue ALL B-frag loads first (one MALL round-trip total) ----
    const ushort_t* xb = ringE + (size_t)(t * 2 + d) * 16384 +
                         wv * 512 + l16 * 32 + kg * 8;
    bf16x8 bfr[8];
#pragma unroll
    for (int ks = 0; ks < 8; ++ks) bfr[ks] = *(const bf16x8*)(xb + ks * 2048);
    float gi[4];
    if (lane < 32) {                  // lands under MFMA latency
#pragma unroll
      for (int r = 0; r < 4; ++r)
        gi[r] = GT[((size_t)s * 2048 + d * 1024 + r * 256 + hu) * 64 + b];
    }
    f32x4 acc = {0.f, 0.f, 0.f, 0.f};
#pragma unroll
    for (int ks = 0; ks < 8; ++ks) {
      bf16x8 af = *(const bf16x8*)(wp + ks * 32);
      acc = __builtin_amdgcn_mfma_f32_16x16x32_bf16(af, bfr[ks], acc, 0, 0, 0);
    }
    if (lane < 32) {
      float g4[4];
#pragma unroll
      for (int r = 0; r < 4; ++r) g4[r] = acc[r] + gi[r];
      float ig = sigf(g4[0]), fg = sigf(g4[1]), gg = tanhf(g4[2]), og = sigf(g4[3]);
      creg = fg * creg + ig * gg;
      float hn = og * tanhf(creg);
      cstoreh(&ringE[(size_t)((t + 1) * 2 + d) * 16384 + xidx(hu, b)], f2bf(hn));
      if (LOUT == 0)
        ((ushort_t*)lout)[((size_t)s * 64 + b) * 512 + d * 256 + hu] = f2bf(hn);
      else
        ((float*)lout)[(size_t)b * 65536 + (size_t)s * 512 + d * 256 + hu] = hn;
      if (t == SS - 1) {
        hFin[xidx(512 + d * 256 + hu, b)] = f2bf(hn);
        cFin[(d * 256 + hu) * 64 + b] = creg;
      }
    }
    if (t < SS - 1) gbar(bar, (unsigned)(t + 1));
  }
}

// ---------------------------------------------------------------------------
// Persistent decoder: 128 steps x {cell0, cell1, attention, outproj}.
// bf16 rings [slot][frag-native 64x1024]: r0=[feed|h0], r1=[h0|h1], r2=[ctx|h1].
__global__ __launch_bounds__(256, 1) void dec_persist(
    const float* __restrict__ GdT,    // [128][2048][64] emb gates fp32
    const float* __restrict__ w_ih0, const float* __restrict__ w_hh0,
    const float* __restrict__ w_ih1, const float* __restrict__ w_hh1,
    const float* __restrict__ b_ih1, const float* __restrict__ b_hh1,
    const float* __restrict__ attn_w,
    const float* __restrict__ enc_out,   // [64][128][512] fp32
    const int* __restrict__ src_tokens,
    const float* __restrict__ c0T, const float* __restrict__ c1T,  // [512][64]
    ushort_t* __restrict__ r0, ushort_t* __restrict__ r1,
    ushort_t* __restrict__ r2,
    float* __restrict__ houts,        // [8192][512] fp32
    unsigned* bar) {
  int nb = blockIdx.x;
  int tid = threadIdx.x;
  int lane = tid & 63;
  int wv = __builtin_amdgcn_readfirstlane(tid >> 6);
  int l16 = lane & 15, kg = lane >> 4;
  __shared__ ushort_t wAl[16 * 1032];
  __shared__ ushort_t wBl[16 * 1032];
  __shared__ ushort_t wDl[16 * 1032];
  __shared__ float h1s[512];
  __shared__ float sc[128];

  // ---- stage bf16 weights (once). Rows 0-3: gates hu=nb; 4-7: hu=nb+256.
  for (int idx = tid; idx < 16384; idx += 256) {
    int m = idx >> 10, k = idx & 1023;
    float va = 0.f, vb = 0.f, vd = 0.f;
    if (m < 8) {
      int row = (m & 3) * 512 + nb + 256 * (m >> 2);
      va = (k < 512) ? w_ih0[(size_t)row * 1024 + 512 + k]
                     : w_hh0[(size_t)row * 512 + (k - 512)];
      vb = (k < 512) ? w_ih1[(size_t)row * 512 + k]
                     : w_hh1[(size_t)row * 512 + (k - 512)];
    }
    if (m < 2) vd = attn_w[(size_t)(nb * 2 + m) * 1024 + k];
    wAl[m * 1032 + k] = f2bf(va);
    wBl[m * 1032 + k] = f2bf(vb);
    wDl[m * 1032 + k] = f2bf(vd);
  }
  __syncthreads();

  int b = wv * 16 + l16;
  int hu = nb + 256 * kg;             // epilogue lanes (<32)
  float c0r = 0.f, c1r = 0.f, bias1[4] = {0.f, 0.f, 0.f, 0.f};
  if (lane < 32) {
    c0r = c0T[hu * 64 + b];
    c1r = c1T[hu * 64 + b];
#pragma unroll
    for (int r = 0; r < 4; ++r)
      bias1[r] = b_ih1[r * 512 + hu] + b_hh1[r * 512 + hu];
  }
  const ushort_t* wpA = wAl + l16 * 1032 + kg * 8;
  const ushort_t* wpB = wBl + l16 * 1032 + kg * 8;
  const ushort_t* wpD = wDl + l16 * 1032 + kg * 8;
  int fragoff = wv * 512 + l16 * 32 + kg * 8;   // frag-native wave base

  for (int t = 0; t < TT; ++t) {
    unsigned gb = (unsigned)(t * 4);
    size_t sC = (size_t)t * 65536, sN = (size_t)(t + 1) * 65536;
    // ---- A: cell0 (x = [feed(t)|h0(t)] = r0 slot t) ----
    {
      const ushort_t* xb = r0 + sC + fragoff;
      bf16x8 bfr[32];
#pragma unroll
      for (int ks = 0; ks < 32; ++ks) bfr[ks] = *(const bf16x8*)(xb + ks * 2048);
      float giA[4];
      if (lane < 32) {
#pragma unroll
        for (int r = 0; r < 4; ++r)
          giA[r] = GdT[((size_t)t * 2048 + r * 512 + hu) * 64 + b];
      }
      f32x4 acc = {0.f, 0.f, 0.f, 0.f};
#pragma unroll
      for (int ks = 0; ks < 32; ++ks) {
        bf16x8 af = *(const bf16x8*)(wpA + ks * 32);
        acc = __builtin_amdgcn_mfma_f32_16x16x32_bf16(af, bfr[ks], acc, 0, 0, 0);
      }
      if (lane < 32) {
        float g4[4];
#pragma unroll
        for (int r = 0; r < 4; ++r) g4[r] = acc[r] + giA[r];
        float ig = sigf(g4[0]), fg = sigf(g4[1]), gg = tanhf(g4[2]), og = sigf(g4[3]);
        c0r = fg * c0r + ig * gg;
        float hn = og * tanhf(c0r);
        ushort_t hb = f2bf(hn);
        cstoreh(&r0[sN + xidx(512 + hu, b)], hb);
        cstoreh(&r1[sC + xidx(hu, b)], hb);
      }
    }
    gbar(bar, gb + 1);
    // ---- B: cell1 (x = [h0(t)|h1(t-1)] = r1 slot t) ----
    {
      const ushort_t* xb = r1 + sC + fragoff;
      bf16x8 bfr[32];
#pragma unroll
      for (int ks = 0; ks < 32; ++ks) bfr[ks] = *(const bf16x8*)(xb + ks * 2048);
      f32x4 acc = {0.f, 0.f, 0.f, 0.f};
#pragma unroll
      for (int ks = 0; ks < 32; ++ks) {
        bf16x8 af = *(const bf16x8*)(wpB + ks * 32);
        acc = __builtin_amdgcn_mfma_f32_16x16x32_bf16(af, bfr[ks], acc, 0, 0, 0);
      }
      if (lane < 32) {
        float g4[4];
#pragma unroll
        for (int r = 0; r < 4; ++r) g4[r] = acc[r] + bias1[r];
        float ig = sigf(g4[0]), fg = sigf(g4[1]), gg = tanhf(g4[2]), og = sigf(g4[3]);
        c1r = fg * c1r + ig * gg;
        float hn = og * tanhf(c1r);
        ushort_t hb = f2bf(hn);
        cstoreh(&r1[sN + xidx(512 + hu, b)], hb);
        cstoreh(&r2[sC + xidx(512 + hu, b)], hb);
      }
    }
    gbar(bar, gb + 2);
    // ---- C: attention (blocks 0..63, one per batch; fp32) ----
    if (nb < 64) {
      const float* eb = enc_out + (size_t)nb * 65536;
      for (int i = tid; i < 512; i += 256)
        h1s[i] = bf2f(r1[sN + xidx(512 + i, nb)]);
      __syncthreads();
      {
        int s2 = tid >> 1, half = tid & 1;
        const float* er = eb + (size_t)s2 * 512 + half * 256;
        const float* hh = h1s + half * 256;
        float a = 0.f;
#pragma unroll 8
        for (int k = 0; k < 256; k += 4) {
          float4 ev = *(const float4*)&er[k];
          a += ev.x * hh[k] + ev.y * hh[k + 1] + ev.z * hh[k + 2] + ev.w * hh[k + 3];
        }
        a += __shfl_xor(a, 1);
        if (!half) sc[s2] = (src_tokens[nb * SS + s2] == 0) ? -1e30f : a;
      }
      __syncthreads();
      if (tid < 64) {
        float m = fmaxf(sc[tid], sc[tid + 64]);
        for (int off = 32; off; off >>= 1) m = fmaxf(m, __shfl_xor(m, off));
        float e0 = __expf(sc[tid] - m), e1 = __expf(sc[tid + 64] - m);
        float ssum = e0 + e1;
        for (int off = 32; off; off >>= 1) ssum += __shfl_xor(ssum, off);
        float inv = 1.f / ssum;
        sc[tid] = e0 * inv; sc[tid + 64] = e1 * inv;
      }
      __syncthreads();
      float a0 = 0.f, a1 = 0.f;
      for (int s2 = 0; s2 < 128; ++s2) {
        float p_ = sc[s2];
        const float* er = eb + (size_t)s2 * 512;
        a0 += p_ * er[tid];
        a1 += p_ * er[tid + 256];
      }
      cstoreh(&r2[sC + xidx(tid, nb)], f2bf(a0));
      cstoreh(&r2[sC + xidx(tid + 256, nb)], f2bf(a1));
    }
    gbar(bar, gb + 3);
    // ---- D: outproj tanh([ctx|h1] @ attn_w^T) -> feed + houts ----
    {
      const ushort_t* xb = r2 + sC + fragoff;
      bf16x8 bfr[32];
#pragma unroll
      for (int ks = 0; ks < 32; ++ks) bfr[ks] = *(const bf16x8*)(xb + ks * 2048);
      f32x4 acc = {0.f, 0.f, 0.f, 0.f};
#pragma unroll
      for (int ks = 0; ks < 32; ++ks) {
        bf16x8 af = *(const bf16x8*)(wpD + ks * 32);
        acc = __builtin_amdgcn_mfma_f32_16x16x32_bf16(af, bfr[ks], acc, 0, 0, 0);
      }
      if (lane < 16) {   // rows 0,1 live in lanes 0-15, regs 0-1
#pragma unroll
        for (int r = 0; r < 2; ++r) {
          int o = nb * 2 + r;
          float v = tanhf(acc[r]);
          cstoreh(&r0[sN + xidx(o, b)], f2bf(v));
          houts[((size_t)t * 64 + b) * 512 + o] = v;
        }
      }
    }
    if (t < TT - 1) gbar(bar, gb + 4);
  }
}

// ---------------------------------------------------------------------------
extern "C" void kernel_launch(void* const* d_in, const int* in_sizes, int n_in,
                              void* d_out, int out_size, void* d_ws, size_t ws_size,
                              hipStream_t stream) {
  const int*   src_tokens = (const int*)d_in[0];
  const int*   dst        = (const int*)d_in[2];
  const float* emb_in     = (const float*)d_in[3];
  const float* emb_out    = (const float*)d_in[4];
  const float* enc_w_ih0  = (const float*)d_in[5];
  const float* enc_w_ih1  = (const float*)d_in[6];
  const float* enc_w_hh   = (const float*)d_in[7];
  const float* enc_b_ih   = (const float*)d_in[8];
  const float* enc_b_hh   = (const float*)d_in[9];
  const float* dec_w_ih0  = (const float*)d_in[10];
  const float* dec_w_hh0  = (const float*)d_in[11];
  const float* dec_b_ih0  = (const float*)d_in[12];
  const float* dec_b_hh0  = (const float*)d_in[13];
  const float* dec_w_ih1  = (const float*)d_in[14];
  const float* dec_w_hh1  = (const float*)d_in[15];
  const float* dec_b_ih1  = (const float*)d_in[16];
  const float* dec_b_hh1  = (const float*)d_in[17];
  const float* attn_w     = (const float*)d_in[18];
  const float* pred_w     = (const float*)d_in[19];
  const float* pred_b     = (const float*)d_in[20];
  float* out = (float*)d_out;

  float* ws      = (float*)d_ws;
  float* houts   = ws;                             // 4,194,304 f
  float* GT      = ws + 4194304;                   // 16,777,216 f
  float* encOut  = ws + 20971520;                  // 4,194,304 f ([b][s][h])
  ushort_t* r0   = (ushort_t*)(ws + 25165824);     // 129*65536 bf16 frag-native
  ushort_t* r1   = (ushort_t*)(ws + 29392896);
  ushort_t* r2   = (ushort_t*)(ws + 33619968);     // 128 slots; doubles as wBF pre-dec
  ushort_t* wBF  = r2;                             // [3][2048][512] bf16 (dead before dec)
  ushort_t* ringE= (ushort_t*)(ws + 37814272);     // 129*2*16384 bf16
  float* c0T     = ws + 39927808;                  // 32,768
  float* c1T     = ws + 39960576;                  // 32,768
  unsigned* barA = (unsigned*)(ws + 39993344);     // 3 x 8192 uints
  unsigned* barB = barA + 8192;
  unsigned* barC = barB + 8192;
  ushort_t* U    = (ushort_t*)(ws + 40017920);     // [8192][512] bf16 staging

  hipMemsetAsync(barA, 0, 3 * 8192 * sizeof(unsigned), stream);
  hipMemsetAsync(r0, 0, 65536 * sizeof(ushort_t), stream);     // slot 0
  hipMemsetAsync(r1, 0, 65536 * sizeof(ushort_t), stream);     // slot 0
  hipMemsetAsync(ringE, 0, 32768 * sizeof(ushort_t), stream);  // slot 0

  // ---- One-time weight cast (wBF aliases r2: dec_persist runs after last use)
  k_castw<<<dim3(2048, 3), 128, 0, stream>>>(enc_w_ih0, enc_w_ih1, dec_w_ih0, wBF);

  // ---- Encoder ----
  k_embed_bf<<<dim3(8192), 128, 0, stream>>>(emb_in, src_tokens, U, SS);
  gemm_bf<<<dim3(16, 64), 256, 0, stream>>>(U, wBF, enc_b_ih, enc_b_hh, GT);
  enc_persist<0><<<dim3(NBLK), 256, 0, stream>>>(GT, enc_w_hh, ringE, U,
                                                 r0, c0T, barA);
  gemm_bf<<<dim3(16, 64), 256, 0, stream>>>(U, wBF + 1048576,
                                            enc_b_ih + 2048, enc_b_hh + 2048, GT);
  enc_persist<1><<<dim3(NBLK), 256, 0, stream>>>(GT, enc_w_hh + 524288, ringE,
                                                 encOut, r1, c1T, barB);

  // ---- Decoder precompute (emb part of cell0 gates) ----
  k_embed_bf<<<dim3(8192), 128, 0, stream>>>(emb_out, dst, U, TT);
  gemm_bf<<<dim3(16, 64), 256, 0, stream>>>(U, wBF + 2097152,
                                            dec_b_ih0, dec_b_hh0, GT);

  // ---- Decoder (persistent, MFMA, frag-native rings, deep load prefetch) ----
  dec_persist<<<dim3(NBLK), 256, 0, stream>>>(
      GT, dec_w_ih0, dec_w_hh0, dec_w_ih1, dec_w_hh1, dec_b_ih1, dec_b_hh1,
      attn_w, encOut, src_tokens, c0T, c1T, r0, r1, r2, houts, barC);

  // ---- Final projection straight to [B][OUT][T] ----
  k_gemm2<<<dim3(4, 64), 256, 0, stream>>>(houts, pred_w, pred_b, out, 512);
}

// Round 14
// 4320.056 us; speedup vs baseline: 1.6050x; 1.1246x over previous
//
#include <hip/hip_runtime.h>
#include <hip/hip_bf16.h>

#define SS 128
#define TT 128
#define NBLK 256   // encoder grid
#define NBD  128   // decoder grid (full 16-row MFMA tiles)
#define FSTRIDE 16 // one flag per 64B cacheline

typedef __attribute__((ext_vector_type(8))) short bf16x8;
typedef __attribute__((ext_vector_type(4))) float f32x4;
typedef unsigned short ushort_t;

__device__ __forceinline__ float sigf(float x) { return 1.f / (1.f + __expf(-x)); }

__device__ __forceinline__ ushort_t f2bf(float f) {   // RNE f32 -> bf16
  unsigned b = __builtin_bit_cast(unsigned, f);
  return (ushort_t)((b + 0x7FFFu + ((b >> 16) & 1u)) >> 16);
}
__device__ __forceinline__ float bf2f(ushort_t u) {
  return __builtin_bit_cast(float, (unsigned)u << 16);
}

// Write-through coherent bf16 store (to MALL): cross-block producers.
__device__ __forceinline__ void cstoreh(ushort_t* p, ushort_t v) {
  __hip_atomic_store(p, v, __ATOMIC_RELAXED, __HIP_MEMORY_SCOPE_AGENT);
}

// Fragment-native ring index: element (k, b) of an x-slot lives at
//   ((k>>5)*256 + b*4 + ((k>>3)&3))*8 + (k&7)
// -> wave's MFMA B-frag load (lane=(l16,kg), iter ks) is a CONTIGUOUS 1KB.
__device__ __forceinline__ int xidx(int k, int b) {
  return (((k >> 5) * 256 + b * 4 + ((k >> 3) & 3)) << 3) + (k & 7);
}

// ---------------------------------------------------------------------------
// R8 master-relay barrier (best measured), templated on block count.
template<int NB>
__device__ __forceinline__ void gbar(unsigned* flags, unsigned gen) {
  __syncthreads();
  int tid = threadIdx.x;
  unsigned* arr = flags;
  unsigned* go  = flags + NB * FSTRIDE;
  if (blockIdx.x == 0) {
    if (tid > 0 && tid < NB) {
      int guard = 0;
      while (__hip_atomic_load(&arr[tid * FSTRIDE], __ATOMIC_RELAXED,
                               __HIP_MEMORY_SCOPE_AGENT) < gen &&
             ++guard < (1 << 20))
        __builtin_amdgcn_s_sleep(1);
    }
    __syncthreads();
    if (tid < NB)
      __hip_atomic_store(&go[tid * FSTRIDE], gen, __ATOMIC_RELAXED,
                         __HIP_MEMORY_SCOPE_AGENT);
  } else {
    if (tid == 0) {
      asm volatile("s_waitcnt vmcnt(0)" ::: "memory");
      __hip_atomic_store(&arr[blockIdx.x * FSTRIDE], gen, __ATOMIC_RELAXED,
                         __HIP_MEMORY_SCOPE_AGENT);
      int guard = 0;
      while (__hip_atomic_load(&go[blockIdx.x * FSTRIDE], __ATOMIC_RELAXED,
                               __HIP_MEMORY_SCOPE_AGENT) < gen &&
             ++guard < (1 << 20))
        __builtin_amdgcn_s_sleep(1);
    }
    __syncthreads();
  }
  asm volatile("" ::: "memory");
}

// ---------------------------------------------------------------------------
// Embedding gather -> bf16 [seq*64][512]
__global__ void k_embed_bf(const float* __restrict__ emb, const int* __restrict__ toks,
                           ushort_t* __restrict__ out, int seqlen) {
  int s = blockIdx.x >> 6, b = blockIdx.x & 63;
  int tok = toks[b * seqlen + s];
  float4 v = ((const float4*)(emb + (size_t)tok * 512))[threadIdx.x];
  unsigned lo = (unsigned)f2bf(v.x) | ((unsigned)f2bf(v.y) << 16);
  unsigned hi = (unsigned)f2bf(v.z) | ((unsigned)f2bf(v.w) << 16);
  uint2 pk = {lo, hi};
  *(uint2*)&out[(size_t)blockIdx.x * 512 + threadIdx.x * 4] = pk;
}

// Cast weights to bf16. wBF (aliases r2; all reads BEFORE dec_persist):
// slot0=enc_w_ih0[2048][512], slot1=enc_w_ih1, slot2=dec_w_ih0[:, 0:512].
// predBF (separate, NON-aliased: read AFTER dec_persist) = pred_w[512][512].
__global__ void k_castw(const float* __restrict__ s0, const float* __restrict__ s1,
                        const float* __restrict__ s2, const float* __restrict__ s3,
                        ushort_t* __restrict__ wBF, ushort_t* __restrict__ predBF) {
  int row = blockIdx.x, which = blockIdx.y;
  if (which == 3 && row >= 512) return;
  const float* src = (which == 0) ? s0 + (size_t)row * 512
                   : (which == 1) ? s1 + (size_t)row * 512
                   : (which == 2) ? s2 + (size_t)row * 1024
                                  : s3 + (size_t)row * 512;
  float4 v = ((const float4*)src)[threadIdx.x];
  unsigned lo = (unsigned)f2bf(v.x) | ((unsigned)f2bf(v.y) << 16);
  unsigned hi = (unsigned)f2bf(v.z) | ((unsigned)f2bf(v.w) << 16);
  uint2 pk = {lo, hi};
  if (which == 3)
    *(uint2*)&predBF[(size_t)row * 512 + threadIdx.x * 4] = pk;
  else
    *(uint2*)&wBF[((size_t)which * 2048 + row) * 512 + threadIdx.x * 4] = pk;
}

// ---------------------------------------------------------------------------
// bf16 MFMA GEMM, K=512. MODE 1: gate precompute, N=2048,
//   GT[((m>>6)*2048 + n)*64 + (m&63)] = X·W + b1 + b2
// MODE 2: final projection, N=512, out[((m&63)*512+n)*128+(m>>6)] = X·W + b1
__global__ __launch_bounds__(256) void gemm_bf(
    const ushort_t* __restrict__ X, const ushort_t* __restrict__ W,
    const float* __restrict__ b1, const float* __restrict__ b2,
    float* __restrict__ C, int MODE) {
  __shared__ ushort_t Xs[128 * 72];
  __shared__ ushort_t Ws[128 * 72];
  __shared__ float sbias[128];
  int n0 = blockIdx.x * 128, m0 = blockIdx.y * 128;
  int tid = threadIdx.x;
  int lane = tid & 63;
  int wv = __builtin_amdgcn_readfirstlane(tid >> 6);
  int h_m = (wv >> 1) * 64, h_n = (wv & 1) * 64;
  int l16 = lane & 15, l4 = (lane >> 4) * 4, k8 = (lane >> 4) * 8;
  if (tid < 128) sbias[tid] = b1[n0 + tid] + (b2 ? b2[n0 + tid] : 0.f);
  f32x4 acc[4][4] = {};
  int lrow = tid >> 1, lhf = (tid & 1) * 32;
  for (int k0 = 0; k0 < 512; k0 += 64) {
    __syncthreads();
    const ushort_t* xs = X + (size_t)(m0 + lrow) * 512 + k0 + lhf;
    const ushort_t* wsrc = W + (size_t)(n0 + lrow) * 512 + k0 + lhf;
#pragma unroll
    for (int q = 0; q < 4; ++q) {
      *(bf16x8*)&Xs[lrow * 72 + lhf + q * 8] = *(const bf16x8*)(xs + q * 8);
      *(bf16x8*)&Ws[lrow * 72 + lhf + q * 8] = *(const bf16x8*)(wsrc + q * 8);
    }
    __syncthreads();
#pragma unroll
    for (int kk = 0; kk < 2; ++kk) {
#pragma unroll
      for (int mt = 0; mt < 4; ++mt) {
        bf16x8 af = *(const bf16x8*)&Xs[(h_m + mt * 16 + l16) * 72 + kk * 32 + k8];
#pragma unroll
        for (int nt = 0; nt < 4; ++nt) {
          bf16x8 bf = *(const bf16x8*)&Ws[(h_n + nt * 16 + l16) * 72 + kk * 32 + k8];
          acc[mt][nt] = __builtin_amdgcn_mfma_f32_16x16x32_bf16(af, bf, acc[mt][nt], 0, 0, 0);
        }
      }
    }
  }
  if (MODE == 1) {
    int s = (m0 + h_m) >> 6;
#pragma unroll
    for (int nt = 0; nt < 4; ++nt) {
      int n = n0 + h_n + nt * 16 + l16;
      float bias = sbias[h_n + nt * 16 + l16];
#pragma unroll
      for (int mt = 0; mt < 4; ++mt) {
        f32x4 v = acc[mt][nt];
        v[0] += bias; v[1] += bias; v[2] += bias; v[3] += bias;
        *(f32x4*)&C[((size_t)s * 2048 + n) * 64 + mt * 16 + l4] = v;
      }
    }
  } else {
#pragma unroll
    for (int nt = 0; nt < 4; ++nt) {
      int n = n0 + h_n + nt * 16 + l16;
      float bias = sbias[h_n + nt * 16 + l16];
#pragma unroll
      for (int mt = 0; mt < 4; ++mt) {
#pragma unroll
        for (int r = 0; r < 4; ++r) {
          int m = m0 + h_m + mt * 16 + l4 + r;
          C[((size_t)(m & 63) * 512 + n) * 128 + (m >> 6)] = acc[mt][nt][r] + bias;
        }
      }
    }
  }
}

// ---------------------------------------------------------------------------
// Persistent encoder layer: K=256, ring ringE[129][2][frag-native 64x256].
// LOUT=0: lout bf16 [8192][512] (feeds layer-1 GEMM). LOUT=1: bf16 [64][128][512].
template<int LOUT>
__global__ __launch_bounds__(256, 1) void enc_persist(
    const float* __restrict__ GT,     // [128][2048][64] input gates fp32
    const float* __restrict__ whh,    // [2][1024][256] this layer fp32
    ushort_t* __restrict__ ringE,     // [129][2][16384] bf16 frag-native
    ushort_t* __restrict__ lout,
    ushort_t* __restrict__ hFin,      // dec ring slot0 (frag-native [64][1024])
    float* __restrict__ cFin,         // [512][64] fp32
    unsigned* bar) {
  int nb = blockIdx.x;
  int d = nb >> 7, nbL = nb & 127;
  int tid = threadIdx.x;
  int lane = tid & 63;
  int wv = __builtin_amdgcn_readfirstlane(tid >> 6);
  int l16 = lane & 15, kg = lane >> 4;
  __shared__ ushort_t wE[16 * 264];

  for (int idx = tid; idx < 16 * 256; idx += 256) {
    int m = idx >> 8, k = idx & 255;
    float v = 0.f;
    if (m < 8)
      v = whh[(size_t)d * 262144 +
              (size_t)((m & 3) * 256 + nbL + 128 * (m >> 2)) * 256 + k];
    wE[m * 264 + k] = f2bf(v);
  }
  __syncthreads();

  int b = wv * 16 + l16;
  int hu = nbL + 128 * kg;            // epilogue lanes (<32)
  float creg = 0.f;
  const ushort_t* wp = wE + l16 * 264 + kg * 8;

  for (int t = 0; t < SS; ++t) {
    int s = d ? (SS - 1 - t) : t;
    const ushort_t* xb = ringE + (size_t)(t * 2 + d) * 16384 +
                         wv * 512 + l16 * 32 + kg * 8;
    bf16x8 bfr[8];
#pragma unroll
    for (int ks = 0; ks < 8; ++ks) bfr[ks] = *(const bf16x8*)(xb + ks * 2048);
    float gi[4];
    if (lane < 32) {
#pragma unroll
      for (int r = 0; r < 4; ++r)
        gi[r] = GT[((size_t)s * 2048 + d * 1024 + r * 256 + hu) * 64 + b];
    }
    f32x4 acc = {0.f, 0.f, 0.f, 0.f};
#pragma unroll
    for (int ks = 0; ks < 8; ++ks) {
      bf16x8 af = *(const bf16x8*)(wp + ks * 32);
      acc = __builtin_amdgcn_mfma_f32_16x16x32_bf16(af, bfr[ks], acc, 0, 0, 0);
    }
    if (lane < 32) {
      float g4[4];
#pragma unroll
      for (int r = 0; r < 4; ++r) g4[r] = acc[r] + gi[r];
      float ig = sigf(g4[0]), fg = sigf(g4[1]), gg = tanhf(g4[2]), og = sigf(g4[3]);
      creg = fg * creg + ig * gg;
      float hn = og * tanhf(creg);
      cstoreh(&ringE[(size_t)((t + 1) * 2 + d) * 16384 + xidx(hu, b)], f2bf(hn));
      if (LOUT == 0)
        lout[((size_t)s * 64 + b) * 512 + d * 256 + hu] = f2bf(hn);
      else
        lout[(size_t)b * 65536 + (size_t)s * 512 + d * 256 + hu] = f2bf(hn);
      if (t == SS - 1) {
        hFin[xidx(512 + d * 256 + hu, b)] = f2bf(hn);
        cFin[(d * 256 + hu) * 64 + b] = creg;
      }
    }
    if (t < SS - 1) gbar<NBLK>(bar, (unsigned)(t + 1));
  }
}

// ---------------------------------------------------------------------------
// Persistent decoder, NBD=128 blocks: each block owns 4 hu = {nb+128j},
// 16 MFMA rows = 4 hu x 4 gates (row m = j*4 + g) -- no pad rows.
// Rings (frag-native [64][1024]): r0 = [feed | h0], r1 = [- | h1], r2 = [ctx | -].
// Dedup: A writes h0 once (r0 nxt); B reads it there; B writes h1 once (r1 nxt);
// C and D read h1 from r1 nxt.
__global__ __launch_bounds__(256, 1) void dec_persist(
    const float* __restrict__ GdT,    // [128][2048][64] emb gates fp32
    const float* __restrict__ w_ih0, const float* __restrict__ w_hh0,
    const float* __restrict__ w_ih1, const float* __restrict__ w_hh1,
    const float* __restrict__ b_ih1, const float* __restrict__ b_hh1,
    const float* __restrict__ attn_w,
    const ushort_t* __restrict__ enc_out,   // [64][128][512] bf16
    const int* __restrict__ src_tokens,
    const float* __restrict__ c0T, const float* __restrict__ c1T,  // [512][64]
    ushort_t* __restrict__ r0, ushort_t* __restrict__ r1,
    ushort_t* __restrict__ r2,
    ushort_t* __restrict__ houtsB,    // [8192][512] bf16
    unsigned* bar) {
  int nb = blockIdx.x;                // 0..127
  int tid = threadIdx.x;
  int lane = tid & 63;
  int wv = __builtin_amdgcn_readfirstlane(tid >> 6);
  int l16 = lane & 15, kg = lane >> 4;
  __shared__ ushort_t wAl[16 * 1032];
  __shared__ ushort_t wBl[16 * 1032];
  __shared__ ushort_t wDl[16 * 1032];
  __shared__ float h1s[512];
  __shared__ float sc[128];

  // ---- stage bf16 weights (once). Row m = j*4+g -> hu = nb+128j, gate g.
  for (int idx = tid; idx < 16384; idx += 256) {
    int m = idx >> 10, k = idx & 1023;
    int j = m >> 2, g = m & 3;
    int row = g * 512 + nb + 128 * j;
    float va = (k < 512) ? w_ih0[(size_t)row * 1024 + 512 + k]
                         : w_hh0[(size_t)row * 512 + (k - 512)];
    float vb = (k < 512) ? w_ih1[(size_t)row * 512 + k]
                         : w_hh1[(size_t)row * 512 + (k - 512)];
    float vd = (m < 4) ? attn_w[(size_t)(nb * 4 + m) * 1024 + k] : 0.f;
    wAl[m * 1032 + k] = f2bf(va);
    wBl[m * 1032 + k] = f2bf(vb);
    wDl[m * 1032 + k] = f2bf(vd);
  }
  __syncthreads();

  int b = wv * 16 + l16;
  int hu = nb + 128 * kg;             // this lane's hu (all 64 lanes active)
  float c0r = c0T[hu * 64 + b];
  float c1r = c1T[hu * 64 + b];
  float bias1[4];
#pragma unroll
  for (int r = 0; r < 4; ++r)
    bias1[r] = b_ih1[r * 512 + hu] + b_hh1[r * 512 + hu];
  const ushort_t* wpA = wAl + l16 * 1032 + kg * 8;
  const ushort_t* wpB = wBl + l16 * 1032 + kg * 8;
  const ushort_t* wpD = wDl + l16 * 1032 + kg * 8;
  int fragoff = wv * 512 + l16 * 32 + kg * 8;   // frag-native wave base

  for (int t = 0; t < TT; ++t) {
    unsigned gb = (unsigned)(t * 4);
    size_t sC = (size_t)t * 65536, sN = (size_t)(t + 1) * 65536;
    // ---- A: cell0, x = [feed(t) | h0(t)] = r0 slot t (ks 0..31) ----
    {
      const ushort_t* xb = r0 + sC + fragoff;
      bf16x8 bfr[32];
#pragma unroll
      for (int ks = 0; ks < 32; ++ks) bfr[ks] = *(const bf16x8*)(xb + ks * 2048);
      float giA[4];
#pragma unroll
      for (int r = 0; r < 4; ++r)
        giA[r] = GdT[((size_t)t * 2048 + r * 512 + hu) * 64 + b];
      f32x4 acc = {0.f, 0.f, 0.f, 0.f};
#pragma unroll
      for (int ks = 0; ks < 32; ++ks) {
        bf16x8 af = *(const bf16x8*)(wpA + ks * 32);
        acc = __builtin_amdgcn_mfma_f32_16x16x32_bf16(af, bfr[ks], acc, 0, 0, 0);
      }
      float g4[4];
#pragma unroll
      for (int r = 0; r < 4; ++r) g4[r] = acc[r] + giA[r];
      float ig = sigf(g4[0]), fg = sigf(g4[1]), gg = tanhf(g4[2]), og = sigf(g4[3]);
      c0r = fg * c0r + ig * gg;
      float hn = og * tanhf(c0r);
      cstoreh(&r0[sN + xidx(512 + hu, b)], f2bf(hn));   // h0(t+1-slot)
    }
    gbar<NBD>(bar, gb + 1);
    // ---- B: cell1, x = [h0(t) from r0 nxt | h1(t-1) from r1 cur] ----
    {
      bf16x8 bfr[32];
      const ushort_t* xh0 = r0 + sN + fragoff;
      const ushort_t* xh1 = r1 + sC + fragoff;
#pragma unroll
      for (int ks = 0; ks < 16; ++ks) bfr[ks] = *(const bf16x8*)(xh0 + (16 + ks) * 2048);
#pragma unroll
      for (int ks = 16; ks < 32; ++ks) bfr[ks] = *(const bf16x8*)(xh1 + ks * 2048);
      f32x4 acc = {0.f, 0.f, 0.f, 0.f};
#pragma unroll
      for (int ks = 0; ks < 32; ++ks) {
        bf16x8 af = *(const bf16x8*)(wpB + ks * 32);
        acc = __builtin_amdgcn_mfma_f32_16x16x32_bf16(af, bfr[ks], acc, 0, 0, 0);
      }
      float g4[4];
#pragma unroll
      for (int r = 0; r < 4; ++r) g4[r] = acc[r] + bias1[r];
      float ig = sigf(g4[0]), fg = sigf(g4[1]), gg = tanhf(g4[2]), og = sigf(g4[3]);
      c1r = fg * c1r + ig * gg;
      float hn = og * tanhf(c1r);
      cstoreh(&r1[sN + xidx(512 + hu, b)], f2bf(hn));   // h1(t)
    }
    gbar<NBD>(bar, gb + 2);
    // ---- C: attention (blocks 0..63, one per batch; bf16 enc_out) ----
    if (nb < 64) {
      const ushort_t* eb = enc_out + (size_t)nb * 65536;
      for (int i = tid; i < 512; i += 256)
        h1s[i] = bf2f(r1[sN + xidx(512 + i, nb)]);
      __syncthreads();
      {
        int s2 = tid >> 1, half = tid & 1;
        const ushort_t* er = eb + (size_t)s2 * 512 + half * 256;
        const float* hh = h1s + half * 256;
        float a = 0.f;
#pragma unroll 4
        for (int k = 0; k < 256; k += 8) {
          bf16x8 ev = *(const bf16x8*)(er + k);
#pragma unroll
          for (int i = 0; i < 8; ++i)
            a += bf2f((ushort_t)ev[i]) * hh[k + i];
        }
        a += __shfl_xor(a, 1);
        if (!half) sc[s2] = (src_tokens[nb * SS + s2] == 0) ? -1e30f : a;
      }
      __syncthreads();
      if (tid < 64) {
        float m = fmaxf(sc[tid], sc[tid + 64]);
        for (int off = 32; off; off >>= 1) m = fmaxf(m, __shfl_xor(m, off));
        float e0 = __expf(sc[tid] - m), e1 = __expf(sc[tid + 64] - m);
        float ssum = e0 + e1;
        for (int off = 32; off; off >>= 1) ssum += __shfl_xor(ssum, off);
        float inv = 1.f / ssum;
        sc[tid] = e0 * inv; sc[tid + 64] = e1 * inv;
      }
      __syncthreads();
      float a0 = 0.f, a1 = 0.f;
      for (int s2 = 0; s2 < 128; ++s2) {
        float p_ = sc[s2];
        const ushort_t* er = eb + (size_t)s2 * 512;
        a0 += p_ * bf2f(er[tid]);
        a1 += p_ * bf2f(er[tid + 256]);
      }
      cstoreh(&r2[sC + xidx(tid, nb)], f2bf(a0));
      cstoreh(&r2[sC + xidx(tid + 256, nb)], f2bf(a1));
    }
    gbar<NBD>(bar, gb + 3);
    // ---- D: outproj tanh([ctx from r2 cur | h1 from r1 nxt] @ wD^T) ----
    {
      bf16x8 bfr[32];
      const ushort_t* xc = r2 + sC + fragoff;
      const ushort_t* xh1 = r1 + sN + fragoff;
#pragma unroll
      for (int ks = 0; ks < 16; ++ks) bfr[ks] = *(const bf16x8*)(xc + ks * 2048);
#pragma unroll
      for (int ks = 16; ks < 32; ++ks) bfr[ks] = *(const bf16x8*)(xh1 + ks * 2048);
      f32x4 acc = {0.f, 0.f, 0.f, 0.f};
#pragma unroll
      for (int ks = 0; ks < 32; ++ks) {
        bf16x8 af = *(const bf16x8*)(wpD + ks * 32);
        acc = __builtin_amdgcn_mfma_f32_16x16x32_bf16(af, bfr[ks], acc, 0, 0, 0);
      }
      if (lane < 16) {   // rows 0-3 (o = nb*4+r) live in lanes 0-15
#pragma unroll
        for (int r = 0; r < 4; ++r) {
          int o = nb * 4 + r;
          float v = tanhf(acc[r]);
          ushort_t vb = f2bf(v);
          cstoreh(&r0[sN + xidx(o, b)], vb);            // feed(t+1-slot)
          houtsB[((size_t)t * 64 + b) * 512 + o] = vb;
        }
      }
    }
    if (t < TT - 1) gbar<NBD>(bar, gb + 4);
  }
}

// ---------------------------------------------------------------------------
extern "C" void kernel_launch(void* const* d_in, const int* in_sizes, int n_in,
                              void* d_out, int out_size, void* d_ws, size_t ws_size,
                              hipStream_t stream) {
  const int*   src_tokens = (const int*)d_in[0];
  const int*   dst        = (const int*)d_in[2];
  const float* emb_in     = (const float*)d_in[3];
  const float* emb_out    = (const float*)d_in[4];
  const float* enc_w_ih0  = (const float*)d_in[5];
  const float* enc_w_ih1  = (const float*)d_in[6];
  const float* enc_w_hh   = (const float*)d_in[7];
  const float* enc_b_ih   = (const float*)d_in[8];
  const float* enc_b_hh   = (const float*)d_in[9];
  const float* dec_w_ih0  = (const float*)d_in[10];
  const float* dec_w_hh0  = (const float*)d_in[11];
  const float* dec_b_ih0  = (const float*)d_in[12];
  const float* dec_b_hh0  = (const float*)d_in[13];
  const float* dec_w_ih1  = (const float*)d_in[14];
  const float* dec_w_hh1  = (const float*)d_in[15];
  const float* dec_b_ih1  = (const float*)d_in[16];
  const float* dec_b_hh1  = (const float*)d_in[17];
  const float* attn_w     = (const float*)d_in[18];
  const float* pred_w     = (const float*)d_in[19];
  const float* pred_b     = (const float*)d_in[20];
  float* out = (float*)d_out;

  float* ws       = (float*)d_ws;
  ushort_t* houtsB = (ushort_t*)ws;                 // [8192][512] bf16
  float* GT       = ws + 4194304;                   // 16,777,216 f
  ushort_t* encOutB = (ushort_t*)(ws + 20971520);   // [64][128][512] bf16 (2,097,152 f)
  ushort_t* predBF  = (ushort_t*)(ws + 23068672);   // [512][512] bf16 -- NOT aliased
  ushort_t* r0    = (ushort_t*)(ws + 25165824);     // 129*65536 bf16 frag-native
  ushort_t* r1    = (ushort_t*)(ws + 29392896);
  ushort_t* r2    = (ushort_t*)(ws + 33619968);     // 128 slots; wBF alias pre-dec
  ushort_t* wBF   = r2;                             // [3][2048][512] bf16 (reads all pre-dec)
  ushort_t* ringE = (ushort_t*)(ws + 37814272);     // 129*2*16384 bf16
  float* c0T      = ws + 39927808;                  // 32,768
  float* c1T      = ws + 39960576;                  // 32,768
  unsigned* barA  = (unsigned*)(ws + 39993344);     // 3 x 8192 uints
  unsigned* barB  = barA + 8192;
  unsigned* barC  = barB + 8192;                    // dec uses 2*128*16 = 4096
  ushort_t* U     = (ushort_t*)(ws + 40017920);     // [8192][512] bf16 staging

  hipMemsetAsync(barA, 0, 3 * 8192 * sizeof(unsigned), stream);
  hipMemsetAsync(r0, 0, 65536 * sizeof(ushort_t), stream);     // slot 0
  hipMemsetAsync(r1, 0, 65536 * sizeof(ushort_t), stream);     // slot 0
  hipMemsetAsync(ringE, 0, 32768 * sizeof(ushort_t), stream);  // slot 0

  // ---- One-time weight cast (wBF aliases r2 -- consumed before dec;
  //      pred_w goes to predBF which nothing else touches)
  k_castw<<<dim3(2048, 4), 128, 0, stream>>>(enc_w_ih0, enc_w_ih1, dec_w_ih0,
                                             pred_w, wBF, predBF);

  // ---- Encoder ----
  k_embed_bf<<<dim3(8192), 128, 0, stream>>>(emb_in, src_tokens, U, SS);
  gemm_bf<<<dim3(16, 64), 256, 0, stream>>>(U, wBF, enc_b_ih, enc_b_hh, GT, 1);
  enc_persist<0><<<dim3(NBLK), 256, 0, stream>>>(GT, enc_w_hh, ringE, U,
                                                 r0, c0T, barA);
  gemm_bf<<<dim3(16, 64), 256, 0, stream>>>(U, wBF + 1048576,
                                            enc_b_ih + 2048, enc_b_hh + 2048, GT, 1);
  enc_persist<1><<<dim3(NBLK), 256, 0, stream>>>(GT, enc_w_hh + 524288, ringE,
                                                 encOutB, r1, c1T, barB);

  // ---- Decoder precompute (emb part of cell0 gates) ----
  k_embed_bf<<<dim3(8192), 128, 0, stream>>>(emb_out, dst, U, TT);
  gemm_bf<<<dim3(16, 64), 256, 0, stream>>>(U, wBF + 2097152,
                                            dec_b_ih0, dec_b_hh0, GT, 1);

  // ---- Decoder (persistent, 128 blocks, full 16-row tiles) ----
  dec_persist<<<dim3(NBD), 256, 0, stream>>>(
      GT, dec_w_ih0, dec_w_hh0, dec_w_ih1, dec_w_hh1, dec_b_ih1, dec_b_hh1,
      attn_w, encOutB, src_tokens, c0T, c1T, r0, r1, r2, houtsB, barC);

  // ---- Final projection (bf16 MFMA) straight to [B][OUT][T] ----
  gemm_bf<<<dim3(4, 64), 256, 0, stream>>>(houtsB, predBF,
                                           pred_b, nullptr, out, 2);
}